// Round 5
// baseline (1356.284 us; speedup 1.0000x reference)
//
#include <hip/hip_runtime.h>
#include <math.h>

#define BB   32
#define TT   512
#define DIM  512
#define HID  1024
#define QQ   8
#define CC   256
#define DD   256
#define BT   16384
#define EPSB 1e-5f

typedef _Float16 half4 __attribute__((ext_vector_type(4)));
typedef _Float16 half8 __attribute__((ext_vector_type(8)));
typedef float f32x4 __attribute__((ext_vector_type(4)));

#define GLOAD_LDS16(g, l)                                                      \
  __builtin_amdgcn_global_load_lds(                                            \
      (const __attribute__((address_space(1))) void*)(g),                      \
      (__attribute__((address_space(3))) void*)(l), 16, 0, 0)

// XCD-aware block relabel (proven round 3): group all blocks sharing an
// A-panel onto one XCD. Bijective since gridDim.y % 8 == 0.
__device__ inline void xcd_swizzle(int& bx, int& by) {
  int gx = gridDim.x, gy = gridDim.y;
  int h = blockIdx.x + gx * blockIdx.y;
  int c = h & 7, idx = h >> 3;
  bx = idx % gx;
  by = c * (gy >> 3) + idx / gx;
}

// ---------------------------------------------------------------------------
// Transpose x (B, DIM, T) -> xt (B*T, DIM) fp32 + split f16 (hi, lo)
// ---------------------------------------------------------------------------
__global__ __launch_bounds__(256) void transpose_xt(const float* __restrict__ x,
                                                    float* __restrict__ xt,
                                                    _Float16* __restrict__ xhi,
                                                    _Float16* __restrict__ xlo) {
  __shared__ float tile[32][33];
  int tx = threadIdx.x, ty = threadIdx.y;
  int b = blockIdx.z;
  int t0 = blockIdx.x * 32, c0 = blockIdx.y * 32;
  const float* xb = x + (size_t)b * DIM * TT;
#pragma unroll
  for (int j = 0; j < 32; j += 8)
    tile[ty + j][tx] = xb[(size_t)(c0 + ty + j) * TT + (t0 + tx)];
  __syncthreads();
#pragma unroll
  for (int j = 0; j < 32; j += 8) {
    float v = tile[tx][ty + j];
    size_t gi = ((size_t)b * TT + t0 + ty + j) * DIM + (c0 + tx);
    xt[gi] = v;
    _Float16 h = (_Float16)v;
    xhi[gi] = h;
    xlo[gi] = (_Float16)(v - (float)h);
  }
}

// ---------------------------------------------------------------------------
// Merged weight prep: dec_w0/dec_w1/fin_w -> f16; enc_w0/enc_w1 -> x64 split
// ---------------------------------------------------------------------------
__device__ inline void conv4(const float* __restrict__ in,
                             _Float16* __restrict__ o, int i) {
  float4 v = ((const float4*)in)[i];
  half4 hv;
  hv.x = (_Float16)v.x; hv.y = (_Float16)v.y;
  hv.z = (_Float16)v.z; hv.w = (_Float16)v.w;
  ((half4*)o)[i] = hv;
}

__device__ inline void split4(const float* __restrict__ in,
                              _Float16* __restrict__ hi,
                              _Float16* __restrict__ lo, int i, float scale) {
  float4 v = ((const float4*)in)[i];
  v.x *= scale; v.y *= scale; v.z *= scale; v.w *= scale;
  half4 hv, lv;
  hv.x = (_Float16)v.x; lv.x = (_Float16)(v.x - (float)hv.x);
  hv.y = (_Float16)v.y; lv.y = (_Float16)(v.y - (float)hv.y);
  hv.z = (_Float16)v.z; lv.z = (_Float16)(v.z - (float)hv.z);
  hv.w = (_Float16)v.w; lv.w = (_Float16)(v.w - (float)hv.w);
  ((half4*)hi)[i] = hv;
  ((half4*)lo)[i] = lv;
}

__global__ __launch_bounds__(256) void prep_weights(
    const float* __restrict__ dw0, const float* __restrict__ dw1,
    const float* __restrict__ fw, const float* __restrict__ ew0,
    const float* __restrict__ ew1, _Float16* __restrict__ w0h,
    _Float16* __restrict__ w1h, _Float16* __restrict__ wfh,
    _Float16* __restrict__ w0hi, _Float16* __restrict__ w0lo,
    _Float16* __restrict__ w1hi, _Float16* __restrict__ w1lo) {
  int b = blockIdx.x, t = threadIdx.x;
  if (b < 256) {
    conv4(dw0, w0h, b * 256 + t);
  } else if (b < 1280) {
    conv4(dw1, w1h, (b - 256) * 256 + t);
  } else if (b < 1792) {
    conv4(fw, wfh, (b - 1280) * 256 + t);
  } else if (b < 2304) {
    split4(ew0, w0hi, w0lo, (b - 1792) * 256 + t, 64.f);
  } else {
    split4(ew1, w1hi, w1lo, (b - 2304) * 256 + t, 64.f);
  }
}

// ---------------------------------------------------------------------------
// Wfold = blockdiag(cb_q) @ wo : NN GEMM. Tiny (1.1 GF).
// ---------------------------------------------------------------------------
__global__ __launch_bounds__(256) void fold_w(const float* __restrict__ cb,
                                              const float* __restrict__ wo,
                                              float* __restrict__ Wf) {
  __shared__ float As[8][128];
  __shared__ float Ws[8][128];
  const int tid = threadIdx.x;
  const int n0 = blockIdx.x * 128;
  const int m0 = blockIdx.y * 128;
  const int q = m0 >> 8;
  const int lr = tid >> 1, lk = (tid & 1) << 2;
  const float* Ap = cb + (size_t)q * CC * DD + (size_t)((m0 & 255) + lr) * DD + lk;
  const int br = tid >> 5, bc = (tid & 31) << 2;
  const float* Bp = wo + (size_t)(q * CC + br) * HID + n0 + bc;
  const int tm = (tid >> 4) << 3, tn = (tid & 15) << 3;

  float acc[8][8];
#pragma unroll
  for (int i = 0; i < 8; i++)
#pragma unroll
    for (int j = 0; j < 8; j++) acc[i][j] = 0.f;

  for (int kb = 0; kb < DD; kb += 8) {
    float4 av = *(const float4*)(Ap + kb);
    float4 bb = *(const float4*)(Bp + (size_t)kb * HID);
    __syncthreads();
    As[lk + 0][lr] = av.x; As[lk + 1][lr] = av.y;
    As[lk + 2][lr] = av.z; As[lk + 3][lr] = av.w;
    *(float4*)&Ws[br][bc] = bb;
    __syncthreads();
#pragma unroll
    for (int k = 0; k < 8; ++k) {
      float a[8], b[8];
      *(float4*)(a) = *(const float4*)(&As[k][tm]);
      *(float4*)(a + 4) = *(const float4*)(&As[k][tm + 4]);
      *(float4*)(b) = *(const float4*)(&Ws[k][tn]);
      *(float4*)(b + 4) = *(const float4*)(&Ws[k][tn + 4]);
#pragma unroll
      for (int i = 0; i < 8; i++)
#pragma unroll
        for (int j = 0; j < 8; j++) acc[i][j] = fmaf(a[i], b[j], acc[i][j]);
    }
  }
#pragma unroll
  for (int i = 0; i < 8; i++) {
    float* Cp = Wf + (size_t)(m0 + tm + i) * HID + (n0 + tn);
    float4 o;
    o.x = acc[i][0]; o.y = acc[i][1]; o.z = acc[i][2]; o.w = acc[i][3];
    *(float4*)Cp = o;
    o.x = acc[i][4]; o.y = acc[i][5]; o.z = acc[i][6]; o.w = acc[i][7];
    *(float4*)(Cp + 4) = o;
  }
}

// bfold[q*256+c] = sum_d cb[q,c,d] * bo[q*256+d]
__global__ __launch_bounds__(256) void fold_b(const float* __restrict__ cb,
                                              const float* __restrict__ bo,
                                              float* __restrict__ bf) {
  int q = blockIdx.x, c = threadIdx.x;
  const float* row = cb + ((size_t)q * CC + c) * DD;
  const float* b = bo + q * DD;
  float s = 0.f;
  for (int d = 0; d < DD; d++) s = fmaf(row[d], b[d], s);
  bf[q * CC + c] = s;
}

// ---------------------------------------------------------------------------
// Encoder split-f16 3-term MFMA NT GEMM, XCD-swizzled. BK=64 (half the
// barrier/drain count vs round 2-4's BK=32; LDS 64 KB keeps 2 blocks/CU).
// ---------------------------------------------------------------------------
__global__ __launch_bounds__(256, 2) void hgemm3s_nt(
    const _Float16* __restrict__ Ahi, const _Float16* __restrict__ Alo,
    const _Float16* __restrict__ Whi, const _Float16* __restrict__ Wlo,
    const float* __restrict__ bias, float invsc, _Float16* __restrict__ Chi,
    _Float16* __restrict__ Clo, int ldc, int K, float* __restrict__ stats,
    int N) {
  __shared__ _Float16 Ah[8 * 128 * 8];   // 16 KB each
  __shared__ _Float16 Al[8 * 128 * 8];
  __shared__ _Float16 Bh[8 * 128 * 8];
  __shared__ _Float16 Bl[8 * 128 * 8];
  int BX, BY;
  xcd_swizzle(BX, BY);
  const int tid = threadIdx.x;
  const int l = tid & 63;
  const int w = tid >> 6;
  const int m0 = BY * 128, n0 = BX * 128;
  const int wrow = (w >> 1) * 64, wcol = (w & 1) * 64;

  // slot s = tid + 256*p (p=0..3): row = tid&127, kp = (tid>>7) + 2p
  const int r_ = tid & 127, kp_ = tid >> 7;
  size_t ao[4], wo_[4];
#pragma unroll
  for (int p = 0; p < 4; p++) {
    ao[p] = (size_t)(m0 + r_) * K + (kp_ + 2 * p) * 8;
    wo_[p] = (size_t)(n0 + r_) * K + (kp_ + 2 * p) * 8;
  }

  f32x4 acc[4][4] = {};

  for (int kb = 0; kb < K; kb += 64) {
    __syncthreads();
#pragma unroll
    for (int p = 0; p < 4; p++) {
      GLOAD_LDS16(Ahi + ao[p] + kb, &Ah[(tid + 256 * p) * 8]);
      GLOAD_LDS16(Alo + ao[p] + kb, &Al[(tid + 256 * p) * 8]);
      GLOAD_LDS16(Whi + wo_[p] + kb, &Bh[(tid + 256 * p) * 8]);
      GLOAD_LDS16(Wlo + wo_[p] + kb, &Bl[(tid + 256 * p) * 8]);
    }
    __syncthreads();
#pragma unroll
    for (int ks = 0; ks < 2; ks++) {
      half8 ah[4], al[4], bh[4], bl[4];
#pragma unroll
      for (int i = 0; i < 4; i++) {
        const int idx = ((ks * 4 + (l >> 4)) * 128 + wrow + i * 16 + (l & 15)) * 8;
        ah[i] = *(const half8*)&Ah[idx];
        al[i] = *(const half8*)&Al[idx];
      }
#pragma unroll
      for (int j = 0; j < 4; j++) {
        const int idx = ((ks * 4 + (l >> 4)) * 128 + wcol + j * 16 + (l & 15)) * 8;
        bh[j] = *(const half8*)&Bh[idx];
        bl[j] = *(const half8*)&Bl[idx];
      }
      __builtin_amdgcn_s_setprio(1);
#pragma unroll
      for (int i = 0; i < 4; i++)
#pragma unroll
        for (int j = 0; j < 4; j++) {
          acc[i][j] = __builtin_amdgcn_mfma_f32_16x16x32_f16(ah[i], bh[j],
                                                             acc[i][j], 0, 0, 0);
          acc[i][j] = __builtin_amdgcn_mfma_f32_16x16x32_f16(al[i], bh[j],
                                                             acc[i][j], 0, 0, 0);
          acc[i][j] = __builtin_amdgcn_mfma_f32_16x16x32_f16(ah[i], bl[j],
                                                             acc[i][j], 0, 0, 0);
        }
      __builtin_amdgcn_s_setprio(0);
    }
  }

#pragma unroll
  for (int j = 0; j < 4; j++) {
    const int col = n0 + wcol + j * 16 + (l & 15);
    const float bb = bias[col];
    float s1v = 0.f, s2v = 0.f;
#pragma unroll
    for (int i = 0; i < 4; i++) {
#pragma unroll
      for (int r = 0; r < 4; r++) {
        float v = fmaf(acc[i][j][r], invsc, bb);
        const int row = m0 + wrow + i * 16 + ((l >> 4) << 2) + r;
        _Float16 hv = (_Float16)v;
        Chi[(size_t)row * ldc + col] = hv;
        Clo[(size_t)row * ldc + col] = (_Float16)(v - (float)hv);
        s1v += v;
        s2v = fmaf(v, v, s2v);
      }
    }
    s1v += __shfl_xor(s1v, 16); s1v += __shfl_xor(s1v, 32);
    s2v += __shfl_xor(s2v, 16); s2v += __shfl_xor(s2v, 32);
    if (l < 16) {
      atomicAdd(&stats[col], s1v);
      atomicAdd(&stats[N + col], s2v);
    }
  }
}

// ---------------------------------------------------------------------------
// split-f16 3-term MFMA GEMM + dual argmax, XCD-swizzled (proven; BK=32 —
// BK=64 would need 104 KB LDS and drop to 1 block/CU). +setprio (T5).
// ---------------------------------------------------------------------------
__global__ __launch_bounds__(512, 4) void hgemm3_wo_argmax(
    const _Float16* __restrict__ Ahi, const _Float16* __restrict__ Alo,
    const _Float16* __restrict__ Whi, const _Float16* __restrict__ Wlo,
    const float* __restrict__ bf, const float* __restrict__ u,
    const float* __restrict__ log_temps, float* __restrict__ out_idx,
    int* __restrict__ idx2) {
  __shared__ _Float16 Ahs[4 * 128 * 8];
  __shared__ _Float16 Als[4 * 128 * 8];
  __shared__ _Float16 Bhs[4 * 256 * 8];
  __shared__ _Float16 Bls[4 * 256 * 8];
  __shared__ float redv[2][128][4];
  __shared__ int   redi[2][128][4];
  int BX, BY;
  xcd_swizzle(BX, BY);
  const int tid = threadIdx.x;
  const int l = tid & 63;
  const int w = tid >> 6;
  const int q = BX;
  const int m0 = BY * 128;
  const int n0 = q * CC;
  const int wrow = (w >> 2) * 64, wcol = (w & 3) * 64;

  const int ar = tid & 127, akp = tid >> 7;
  const _Float16* Agh = Ahi + (size_t)(m0 + ar) * HID + akp * 8;
  const _Float16* Agl = Alo + (size_t)(m0 + ar) * HID + akp * 8;
  _Float16* Ahd = &Ahs[tid * 8];
  _Float16* Ald = &Als[tid * 8];
  const int s0 = tid, s1 = tid + 512;
  const int br0 = s0 & 255, bkp0 = s0 >> 8;
  const int br1 = s1 & 255, bkp1 = s1 >> 8;
  const _Float16* Bgh0 = Whi + (size_t)(n0 + br0) * HID + bkp0 * 8;
  const _Float16* Bgh1 = Whi + (size_t)(n0 + br1) * HID + bkp1 * 8;
  const _Float16* Bgl0 = Wlo + (size_t)(n0 + br0) * HID + bkp0 * 8;
  const _Float16* Bgl1 = Wlo + (size_t)(n0 + br1) * HID + bkp1 * 8;
  _Float16* Bhd0 = &Bhs[s0 * 8]; _Float16* Bhd1 = &Bhs[s1 * 8];
  _Float16* Bld0 = &Bls[s0 * 8]; _Float16* Bld1 = &Bls[s1 * 8];

  f32x4 acc[4][4] = {};

  for (int kb = 0; kb < HID; kb += 32) {
    __syncthreads();
    GLOAD_LDS16(Agh + kb, Ahd);
    GLOAD_LDS16(Agl + kb, Ald);
    GLOAD_LDS16(Bgh0 + kb, Bhd0);
    GLOAD_LDS16(Bgh1 + kb, Bhd1);
    GLOAD_LDS16(Bgl0 + kb, Bld0);
    GLOAD_LDS16(Bgl1 + kb, Bld1);
    __syncthreads();
    half8 ah[4], al[4], bh[4], bl[4];
#pragma unroll
    for (int i = 0; i < 4; i++) {
      const int idx = ((l >> 4) * 128 + wrow + i * 16 + (l & 15)) * 8;
      ah[i] = *(const half8*)&Ahs[idx];
      al[i] = *(const half8*)&Als[idx];
    }
#pragma unroll
    for (int j = 0; j < 4; j++) {
      const int idx = ((l >> 4) * 256 + wcol + j * 16 + (l & 15)) * 8;
      bh[j] = *(const half8*)&Bhs[idx];
      bl[j] = *(const half8*)&Bls[idx];
    }
    __builtin_amdgcn_s_setprio(1);
#pragma unroll
    for (int i = 0; i < 4; i++)
#pragma unroll
      for (int j = 0; j < 4; j++) {
        acc[i][j] = __builtin_amdgcn_mfma_f32_16x16x32_f16(ah[i], bh[j],
                                                           acc[i][j], 0, 0, 0);
        acc[i][j] = __builtin_amdgcn_mfma_f32_16x16x32_f16(al[i], bh[j],
                                                           acc[i][j], 0, 0, 0);
        acc[i][j] = __builtin_amdgcn_mfma_f32_16x16x32_f16(ah[i], bl[j],
                                                           acc[i][j], 0, 0, 0);
      }
    __builtin_amdgcn_s_setprio(0);
  }

  const float scale = expf(-log_temps[q]);
  float bcol[4];
#pragma unroll
  for (int j = 0; j < 4; j++) bcol[j] = bf[n0 + wcol + j * 16 + (l & 15)];

#pragma unroll
  for (int i = 0; i < 4; i++) {
#pragma unroll
    for (int r = 0; r < 4; r++) {
      const int rloc = wrow + i * 16 + ((l >> 4) << 2) + r;
      const int row = m0 + rloc;
      float bvv = -INFINITY; int bi = 0;
      float gv = -INFINITY; int gi = 0;
#pragma unroll
      for (int j = 0; j < 4; j++) {
        const int c = wcol + j * 16 + (l & 15);
        float v = acc[i][j][r] + bcol[j];
        if (v > bvv) { bvv = v; bi = c; }
        float uu = u[(size_t)row * (QQ * CC) + n0 + c];
        float uc = fminf(fmaxf(uu, 1e-9f), 1.0f);
        float g = -logf(-logf(uc) + 1e-20f);
        float y = fmaf(v, scale, g);
        if (y > gv) { gv = y; gi = c; }
      }
#pragma unroll
      for (int off = 1; off < 16; off <<= 1) {
        float b2 = __shfl_xor(bvv, off); int bi2 = __shfl_xor(bi, off);
        if (b2 > bvv || (b2 == bvv && bi2 < bi)) { bvv = b2; bi = bi2; }
        float g2 = __shfl_xor(gv, off); int gi2 = __shfl_xor(gi, off);
        if (g2 > gv || (g2 == gv && gi2 < gi)) { gv = g2; gi = gi2; }
      }
      if ((l & 15) == 0) {
        redv[0][rloc][w & 3] = bvv; redi[0][rloc][w & 3] = bi;
        redv[1][rloc][w & 3] = gv;  redi[1][rloc][w & 3] = gi;
      }
    }
  }
  __syncthreads();
  if (tid < 128) {
    float bv = redv[0][tid][0]; int bi = redi[0][tid][0];
    float gv = redv[1][tid][0]; int gi = redi[1][tid][0];
#pragma unroll
    for (int c = 1; c < 4; c++) {
      float v = redv[0][tid][c];
      if (v > bv) { bv = v; bi = redi[0][tid][c]; }
      float v2 = redv[1][tid][c];
      if (v2 > gv) { gv = v2; gi = redi[1][tid][c]; }
    }
    const int row = m0 + tid;
    out_idx[(size_t)row * QQ + q] = (float)bi;
    idx2[(size_t)row * QQ + q] = gi;
  }
}

// ---------------------------------------------------------------------------
// FP16 MFMA NT GEMM, f16 output + fused col stats (decoder layers). BK=64.
// ---------------------------------------------------------------------------
__global__ __launch_bounds__(256, 2) void hgemm_ntf16(
    const _Float16* __restrict__ A, const _Float16* __restrict__ W,
    const float* __restrict__ bias, _Float16* __restrict__ C, int ldc, int K,
    float* __restrict__ stats, int N) {
  __shared__ _Float16 Al[8 * 128 * 8];
  __shared__ _Float16 Bl[8 * 128 * 8];
  int BX, BY;
  xcd_swizzle(BX, BY);
  const int tid = threadIdx.x;
  const int l = tid & 63;
  const int w = tid >> 6;
  const int m0 = BY * 128, n0 = BX * 128;
  const int wrow = (w >> 1) * 64, wcol = (w & 1) * 64;

  const int r_ = tid & 127, kp_ = tid >> 7;
  size_t ao[4], wo_[4];
#pragma unroll
  for (int p = 0; p < 4; p++) {
    ao[p] = (size_t)(m0 + r_) * K + (kp_ + 2 * p) * 8;
    wo_[p] = (size_t)(n0 + r_) * K + (kp_ + 2 * p) * 8;
  }

  f32x4 acc[4][4] = {};

  for (int kb = 0; kb < K; kb += 64) {
    __syncthreads();
#pragma unroll
    for (int p = 0; p < 4; p++) {
      GLOAD_LDS16(A + ao[p] + kb, &Al[(tid + 256 * p) * 8]);
      GLOAD_LDS16(W + wo_[p] + kb, &Bl[(tid + 256 * p) * 8]);
    }
    __syncthreads();
#pragma unroll
    for (int ks = 0; ks < 2; ks++) {
      half8 af[4], bf[4];
#pragma unroll
      for (int i = 0; i < 4; i++)
        af[i] = *(const half8*)
            &Al[((ks * 4 + (l >> 4)) * 128 + wrow + i * 16 + (l & 15)) * 8];
#pragma unroll
      for (int j = 0; j < 4; j++)
        bf[j] = *(const half8*)
            &Bl[((ks * 4 + (l >> 4)) * 128 + wcol + j * 16 + (l & 15)) * 8];
      __builtin_amdgcn_s_setprio(1);
#pragma unroll
      for (int i = 0; i < 4; i++)
#pragma unroll
        for (int j = 0; j < 4; j++)
          acc[i][j] = __builtin_amdgcn_mfma_f32_16x16x32_f16(af[i], bf[j],
                                                             acc[i][j], 0, 0, 0);
      __builtin_amdgcn_s_setprio(0);
    }
  }

#pragma unroll
  for (int j = 0; j < 4; j++) {
    const int col = n0 + wcol + j * 16 + (l & 15);
    const float bb = bias[col];
    float s1v = 0.f, s2v = 0.f;
#pragma unroll
    for (int i = 0; i < 4; i++) {
#pragma unroll
      for (int r = 0; r < 4; r++) {
        float v = acc[i][j][r] + bb;
        const int row = m0 + wrow + i * 16 + ((l >> 4) << 2) + r;
        C[(size_t)row * ldc + col] = (_Float16)v;
        s1v += v;
        s2v = fmaf(v, v, s2v);
      }
    }
    s1v += __shfl_xor(s1v, 16); s1v += __shfl_xor(s1v, 32);
    s2v += __shfl_xor(s2v, 16); s2v += __shfl_xor(s2v, 32);
    if (l < 16) {
      atomicAdd(&stats[col], s1v);
      atomicAdd(&stats[N + col], s2v);
    }
  }
}

// ---------------------------------------------------------------------------
// Final FP16 MFMA NT GEMM: fp32 output + fused commit loss vs xt. BK=64.
// ---------------------------------------------------------------------------
__global__ __launch_bounds__(256, 2) void hgemm_nt_loss(
    const _Float16* __restrict__ A, const _Float16* __restrict__ W,
    const float* __restrict__ bias, float* __restrict__ C, int ldc, int K,
    const float* __restrict__ xt, float* __restrict__ out_loss) {
  __shared__ _Float16 Al[8 * 128 * 8];
  __shared__ _Float16 Bl[8 * 128 * 8];
  int BX, BY;
  xcd_swizzle(BX, BY);
  const int tid = threadIdx.x;
  const int l = tid & 63;
  const int w = tid >> 6;
  const int m0 = BY * 128, n0 = BX * 128;
  const int wrow = (w >> 1) * 64, wcol = (w & 1) * 64;

  const int r_ = tid & 127, kp_ = tid >> 7;
  size_t ao[4], wo_[4];
#pragma unroll
  for (int p = 0; p < 4; p++) {
    ao[p] = (size_t)(m0 + r_) * K + (kp_ + 2 * p) * 8;
    wo_[p] = (size_t)(n0 + r_) * K + (kp_ + 2 * p) * 8;
  }

  f32x4 acc[4][4] = {};

  for (int kb = 0; kb < K; kb += 64) {
    __syncthreads();
#pragma unroll
    for (int p = 0; p < 4; p++) {
      GLOAD_LDS16(A + ao[p] + kb, &Al[(tid + 256 * p) * 8]);
      GLOAD_LDS16(W + wo_[p] + kb, &Bl[(tid + 256 * p) * 8]);
    }
    __syncthreads();
#pragma unroll
    for (int ks = 0; ks < 2; ks++) {
      half8 af[4], bf[4];
#pragma unroll
      for (int i = 0; i < 4; i++)
        af[i] = *(const half8*)
            &Al[((ks * 4 + (l >> 4)) * 128 + wrow + i * 16 + (l & 15)) * 8];
#pragma unroll
      for (int j = 0; j < 4; j++)
        bf[j] = *(const half8*)
            &Bl[((ks * 4 + (l >> 4)) * 128 + wcol + j * 16 + (l & 15)) * 8];
      __builtin_amdgcn_s_setprio(1);
#pragma unroll
      for (int i = 0; i < 4; i++)
#pragma unroll
        for (int j = 0; j < 4; j++)
          acc[i][j] = __builtin_amdgcn_mfma_f32_16x16x32_f16(af[i], bf[j],
                                                             acc[i][j], 0, 0, 0);
      __builtin_amdgcn_s_setprio(0);
    }
  }

  float ls = 0.f;
#pragma unroll
  for (int j = 0; j < 4; j++) {
    const int col = n0 + wcol + j * 16 + (l & 15);
    const float bb = bias[col];
#pragma unroll
    for (int i = 0; i < 4; i++) {
#pragma unroll
      for (int r = 0; r < 4; r++) {
        float v = acc[i][j][r] + bb;
        const int row = m0 + wrow + i * 16 + ((l >> 4) << 2) + r;
        C[(size_t)row * ldc + col] = v;
        float d = v - xt[(size_t)row * ldc + col];
        ls = fmaf(d, d, ls);
      }
    }
  }
#pragma unroll
  for (int off = 32; off > 0; off >>= 1) ls += __shfl_xor(ls, off);
  if (l == 0)
    atomicAdd(out_loss, ls * (1.0f / ((float)BT * (float)DIM)));
}

// ---------------------------------------------------------------------------
// BatchNorm helpers. bn_finalize re-zeroes the stats accumulator after
// reading, removing the per-layer hipMemsetAsync dispatches.
// ---------------------------------------------------------------------------
__global__ __launch_bounds__(256) void bn_finalize(float* __restrict__ sums,
                                                   const float* __restrict__ gamma,
                                                   const float* __restrict__ beta,
                                                   float* __restrict__ ss, int N) {
  int n = blockIdx.x * 256 + threadIdx.x;
  if (n >= N) return;
  const float invM = 1.0f / (float)BT;
  float mean = sums[n] * invM;
  float var = sums[N + n] * invM - mean * mean;
  float sc = gamma[n] / sqrtf(var + EPSB);
  ss[n] = sc;
  ss[N + n] = beta[n] - mean * sc;
  sums[n] = 0.f;
  sums[N + n] = 0.f;
}

// in-place BN (+relu) on a split (hi, lo) f16 pair
__global__ __launch_bounds__(256) void bn_resplit(_Float16* __restrict__ hi,
                                                  _Float16* __restrict__ lo,
                                                  const float* __restrict__ ss,
                                                  int nmask, int N, long n4,
                                                  int relu) {
  long stride = (long)gridDim.x * 256;
  for (long i = (long)blockIdx.x * 256 + threadIdx.x; i < n4; i += stride) {
    int col = (int)((i << 2) & nmask);
    half4 h = ((half4*)hi)[i];
    half4 L = ((half4*)lo)[i];
    float4 sc = *(const float4*)(ss + col);
    float4 sh = *(const float4*)(ss + N + col);
    float vx = fmaf((float)h.x + (float)L.x, sc.x, sh.x);
    float vy = fmaf((float)h.y + (float)L.y, sc.y, sh.y);
    float vz = fmaf((float)h.z + (float)L.z, sc.z, sh.z);
    float vw = fmaf((float)h.w + (float)L.w, sc.w, sh.w);
    if (relu) {
      vx = fmaxf(vx, 0.f); vy = fmaxf(vy, 0.f);
      vz = fmaxf(vz, 0.f); vw = fmaxf(vw, 0.f);
    }
    half4 hv, lv;
    hv.x = (_Float16)vx; lv.x = (_Float16)(vx - (float)hv.x);
    hv.y = (_Float16)vy; lv.y = (_Float16)(vy - (float)hv.y);
    hv.z = (_Float16)vz; lv.z = (_Float16)(vz - (float)hv.z);
    hv.w = (_Float16)vw; lv.w = (_Float16)(vw - (float)hv.w);
    ((half4*)hi)[i] = hv;
    ((half4*)lo)[i] = lv;
  }
}

// in-place BN (+relu) on an f16 buffer
__global__ __launch_bounds__(256) void bnf16_inplace(_Float16* __restrict__ h,
                                                     const float* __restrict__ ss,
                                                     int nmask, int N, long n4,
                                                     int relu) {
  long stride = (long)gridDim.x * 256;
  for (long i = (long)blockIdx.x * 256 + threadIdx.x; i < n4; i += stride) {
    int col = (int)((i << 2) & nmask);
    half4 v = ((half4*)h)[i];
    float4 sc = *(const float4*)(ss + col);
    float4 sh = *(const float4*)(ss + N + col);
    float vx = fmaf((float)v.x, sc.x, sh.x);
    float vy = fmaf((float)v.y, sc.y, sh.y);
    float vz = fmaf((float)v.z, sc.z, sh.z);
    float vw = fmaf((float)v.w, sc.w, sh.w);
    if (relu) {
      vx = fmaxf(vx, 0.f); vy = fmaxf(vy, 0.f);
      vz = fmaxf(vz, 0.f); vw = fmaxf(vw, 0.f);
    }
    half4 o;
    o.x = (_Float16)vx; o.y = (_Float16)vy;
    o.z = (_Float16)vz; o.w = (_Float16)vw;
    ((half4*)h)[i] = o;
  }
}

// fp32 h -> f16 out with BN scale/shift (+optional relu)
__global__ __launch_bounds__(256) void bn_apply_f16(const float* __restrict__ h,
                                                    const float* __restrict__ ss,
                                                    int nmask, int N, long n4,
                                                    int relu,
                                                    _Float16* __restrict__ o) {
  long stride = (long)gridDim.x * 256;
  for (long i = (long)blockIdx.x * 256 + threadIdx.x; i < n4; i += stride) {
    int col = (int)((i << 2) & nmask);
    float4 v = ((const float4*)h)[i];
    float4 sc = *(const float4*)(ss + col);
    float4 sh = *(const float4*)(ss + N + col);
    v.x = fmaf(v.x, sc.x, sh.x); v.y = fmaf(v.y, sc.y, sh.y);
    v.z = fmaf(v.z, sc.z, sh.z); v.w = fmaf(v.w, sc.w, sh.w);
    if (relu) {
      v.x = fmaxf(v.x, 0.f); v.y = fmaxf(v.y, 0.f);
      v.z = fmaxf(v.z, 0.f); v.w = fmaxf(v.w, 0.f);
    }
    half4 hv;
    hv.x = (_Float16)v.x; hv.y = (_Float16)v.y;
    hv.z = (_Float16)v.z; hv.w = (_Float16)v.w;
    ((half4*)o)[i] = hv;
  }
}

// fp32 -> split (hi, lo) f16 with optional pre-scale (used for Wf)
__global__ __launch_bounds__(256) void conv_split_s(const float* __restrict__ in,
                                                    _Float16* __restrict__ hi,
                                                    _Float16* __restrict__ lo,
                                                    int n4, float scale) {
  int i = blockIdx.x * 256 + threadIdx.x;
  if (i >= n4) return;
  split4(in, hi, lo, i, scale);
}

// ---------------------------------------------------------------------------
// emb[bt, d] = sum_q codebook[q, idx2[bt,q], d]  + fused column stats.
// ---------------------------------------------------------------------------
__global__ __launch_bounds__(256) void emb_gather_stats(
    const float* __restrict__ cb, const int* __restrict__ idx2,
    float* __restrict__ emb, float* __restrict__ sums) {
  __shared__ int k[64][8];
  const int r0 = blockIdx.x * 64;
  const int tid = threadIdx.x;
  for (int t = tid; t < 64 * QQ; t += 256)
    k[t >> 3][t & 7] = idx2[(size_t)(r0 + (t >> 3)) * QQ + (t & 7)];
  __syncthreads();
  const int d = tid;
  float s1 = 0.f, s2 = 0.f;
  for (int rr = 0; rr < 64; rr++) {
    float s = 0.f;
#pragma unroll
    for (int q = 0; q < QQ; q++)
      s += cb[((size_t)(q * CC + k[rr][q])) * DD + d];
    emb[(size_t)(r0 + rr) * DD + d] = s;
    s1 += s;
    s2 = fmaf(s, s, s2);
  }
  atomicAdd(&sums[d], s1);
  atomicAdd(&sums[DD + d], s2);
}

// ---------------------------------------------------------------------------
// Workspace layout (float offsets) — unchanged.
// ---------------------------------------------------------------------------
static const size_t OF_XT = 0;
static const size_t OF_R1 = OF_XT + (size_t)BT * DIM;
static const size_t OF_R2 = OF_R1 + (size_t)BT * HID;
static const size_t OF_WF = OF_R2 + (size_t)BT * HID;
static const size_t OF_BF = OF_WF + (size_t)2048 * HID;
static const size_t OF_EMBH = OF_BF + 2048;
static const size_t OF_HB = OF_EMBH + (size_t)BT * DD / 2;
static const size_t OF_W0H = OF_HB + (size_t)BT * HID / 2;
static const size_t OF_W1H = OF_W0H + (size_t)HID * DD / 2;
static const size_t OF_WFH = OF_W1H + (size_t)HID * HID / 2;
static const size_t OF_I2 = OF_WFH + (size_t)DIM * HID / 2;
static const size_t OF_ST = OF_I2 + (size_t)BT * QQ;
static const size_t OF_SS0 = OF_ST + 4096;
static const size_t OF_SS1 = OF_SS0 + 2048;
static const size_t OF_SSD = OF_SS1 + 2048;
static const size_t OF_SD0 = OF_SSD + 1024;
static const size_t OF_SD1 = OF_SD0 + 2048;

extern "C" void kernel_launch(void* const* d_in, const int* in_sizes, int n_in,
                              void* d_out, int out_size, void* d_ws, size_t ws_size,
                              hipStream_t stream) {
  const float* x        = (const float*)d_in[0];
  const float* u        = (const float*)d_in[1];
  const float* codebook = (const float*)d_in[2];
  const float* log_temps= (const float*)d_in[3];
  const float* enc_w0   = (const float*)d_in[4];
  const float* enc_b0   = (const float*)d_in[5];
  const float* enc_g0   = (const float*)d_in[6];
  const float* enc_be0  = (const float*)d_in[7];
  const float* enc_w1   = (const float*)d_in[8];
  const float* enc_b1   = (const float*)d_in[9];
  const float* enc_g1   = (const float*)d_in[10];
  const float* enc_be1  = (const float*)d_in[11];
  const float* enc_wo   = (const float*)d_in[12];
  const float* enc_bo   = (const float*)d_in[13];
  const float* dec_g    = (const float*)d_in[14];
  const float* dec_be   = (const float*)d_in[15];
  const float* dec_w0   = (const float*)d_in[16];
  const float* dec_b0   = (const float*)d_in[17];
  const float* dec_g0   = (const float*)d_in[18];
  const float* dec_be0  = (const float*)d_in[19];
  const float* dec_w1   = (const float*)d_in[20];
  const float* dec_b1   = (const float*)d_in[21];
  const float* dec_g1   = (const float*)d_in[22];
  const float* dec_be1  = (const float*)d_in[23];
  const float* fin_w    = (const float*)d_in[24];
  const float* fin_b    = (const float*)d_in[25];

  float* ws = (float*)d_ws;
  float* xt = ws + OF_XT;
  float* R1 = ws + OF_R1;
  float* Wf = ws + OF_WF;
  float* bfold = ws + OF_BF;
  _Float16* embh = (_Float16*)(ws + OF_EMBH);
  _Float16* w0h = (_Float16*)(ws + OF_W0H);
  _Float16* w1h = (_Float16*)(ws + OF_W1H);
  _Float16* wfh = (_Float16*)(ws + OF_WFH);
  int* idx2 = (int*)(ws + OF_I2);
  float* st = ws + OF_ST;
  float* ss0 = ws + OF_SS0;
  float* ss1 = ws + OF_SS1;
  float* ssd = ws + OF_SSD;
  float* sd0 = ws + OF_SD0;
  float* sd1 = ws + OF_SD1;

  // aliased split / f16 buffers (lifetimes verified rounds 2-5)
  _Float16* xthi = (_Float16*)(ws + OF_R2);
  _Float16* xtlo = (_Float16*)(ws + OF_R2 + (size_t)BT * DIM / 2);
  _Float16* w0hi = (_Float16*)(ws + OF_R2 + (size_t)BT * DIM);
  _Float16* w0lo = (_Float16*)(ws + OF_R2 + (size_t)BT * DIM + (size_t)HID * DIM / 2);
  _Float16* w1hi = (_Float16*)(ws + OF_R2 + (size_t)BT * DIM + (size_t)HID * DIM);
  _Float16* w1lo = (_Float16*)(ws + OF_R2 + (size_t)BT * DIM + (size_t)HID * DIM +
                               (size_t)HID * HID / 2);
  _Float16* r1hi = (_Float16*)(ws + OF_R1);
  _Float16* r1lo = (_Float16*)(ws + OF_R1 + (size_t)BT * HID / 2);
  _Float16* r2hi = (_Float16*)(ws + OF_HB);
  _Float16* r2lo = (_Float16*)(ws + OF_R2);
  _Float16* wfhi = (_Float16*)(ws + OF_R1);
  _Float16* wflo = (_Float16*)(ws + OF_R1 + (size_t)2048 * HID / 2);
  _Float16* h16a = (_Float16*)(ws + OF_R2);
  _Float16* h16b = (_Float16*)(ws + OF_R2 + (size_t)BT * HID / 2);

  float* out = (float*)d_out;
  float* out_idx = out + (size_t)BT * DIM;
  float* out_loss = out + (size_t)BT * DIM + (size_t)BT * QQ;

  hipMemsetAsync(out_loss, 0, sizeof(float), stream);
  // one-time zero of the stats accumulator (bn_finalize keeps it zeroed
  // between uses, including across graph iterations via dec1's finalize)
  hipMemsetAsync(st, 0, 2 * HID * sizeof(float), stream);

  // weight prep (merged) + codebook folding
  prep_weights<<<dim3(3328), 256, 0, stream>>>(
      dec_w0, dec_w1, fin_w, enc_w0, enc_w1, w0h, w1h, wfh, w0hi, w0lo, w1hi,
      w1lo);
  fold_w<<<dim3(HID / 128, 2048 / 128), 256, 0, stream>>>(codebook, enc_wo, Wf);
  fold_b<<<dim3(QQ), 256, 0, stream>>>(codebook, enc_bo, bfold);

  // 1. transpose (+ split f16 copies of xt)
  transpose_xt<<<dim3(TT / 32, DIM / 32, BB), dim3(32, 8), 0, stream>>>(
      x, xt, xthi, xtlo);

  // 2. enc0: r1 = xt @ enc_w0^T + b0 (split MFMA, stats fused); BN in place
  hgemm3s_nt<<<dim3(HID / 128, BT / 128), 256, 0, stream>>>(
      xthi, xtlo, w0hi, w0lo, enc_b0, 1.f / 64.f, r1hi, r1lo, HID, DIM, st, HID);
  bn_finalize<<<dim3(4), 256, 0, stream>>>(st, enc_g0, enc_be0, ss0, HID);
  bn_resplit<<<dim3(2048), 256, 0, stream>>>(r1hi, r1lo, ss0, HID - 1, HID,
                                             (long)BT * HID / 4, 1);

  // 3. enc1: r2 = r1 @ enc_w1^T + b1 (split MFMA, stats fused); BN in place
  hgemm3s_nt<<<dim3(HID / 128, BT / 128), 256, 0, stream>>>(
      r1hi, r1lo, w1hi, w1lo, enc_b1, 1.f / 64.f, r2hi, r2lo, HID, HID, st, HID);
  conv_split_s<<<dim3(2048 * HID / 4 / 256), 256, 0, stream>>>(
      Wf, wfhi, wflo, 2048 * HID / 4, 1.f);
  bn_finalize<<<dim3(4), 256, 0, stream>>>(st, enc_g1, enc_be1, ss1, HID);
  bn_resplit<<<dim3(2048), 256, 0, stream>>>(r2hi, r2lo, ss1, HID - 1, HID,
                                             (long)BT * HID / 4, 1);

  // 4. split-f16 MFMA wo-GEMM + argmax epilogue
  hgemm3_wo_argmax<<<dim3(QQ, BT / 128), 512, 0, stream>>>(
      r2hi, r2lo, wfhi, wflo, bfold, u, log_temps, out_idx, idx2);

  // 5. emb gather (+fused col stats) + BN -> f16
  emb_gather_stats<<<dim3(BT / 64), 256, 0, stream>>>(codebook, idx2, R1, st);
  bn_finalize<<<dim3(1), 256, 0, stream>>>(st, dec_g, dec_be, ssd, DD);
  bn_apply_f16<<<dim3(2048), 256, 0, stream>>>(R1, ssd, DD - 1, DD,
                                               (long)BT * DD / 4, 0, embh);

  // 6. decoder FFN in f16 MFMA (f16 output + in-place BN)
  hgemm_ntf16<<<dim3(HID / 128, BT / 128), 256, 0, stream>>>(
      embh, w0h, dec_b0, h16a, HID, DD, st, HID);
  bn_finalize<<<dim3(4), 256, 0, stream>>>(st, dec_g0, dec_be0, sd0, HID);
  bnf16_inplace<<<dim3(2048), 256, 0, stream>>>(h16a, sd0, HID - 1, HID,
                                                (long)BT * HID / 4, 1);

  hgemm_ntf16<<<dim3(HID / 128, BT / 128), 256, 0, stream>>>(
      h16a, w1h, dec_b1, h16b, HID, HID, st, HID);
  bn_finalize<<<dim3(4), 256, 0, stream>>>(st, dec_g1, dec_be1, sd1, HID);
  bnf16_inplace<<<dim3(2048), 256, 0, stream>>>(h16b, sd1, HID - 1, HID,
                                                (long)BT * HID / 4, 1);

  // 7. x_reco = h @ fin_w^T + fin_b  (+fused commit loss vs xt)
  hgemm_nt_loss<<<dim3(DIM / 128, BT / 128), 256, 0, stream>>>(
      h16b, wfh, fin_b, out, DIM, HID, xt, out_loss);
}

// Round 6
// 1180.683 us; speedup vs baseline: 1.1487x; 1.1487x over previous
//
#include <hip/hip_runtime.h>
#include <math.h>

#define BB   32
#define TT   512
#define DIM  512
#define HID  1024
#define QQ   8
#define CC   256
#define DD   256
#define BT   16384
#define EPSB 1e-5f

typedef _Float16 half4 __attribute__((ext_vector_type(4)));
typedef _Float16 half8 __attribute__((ext_vector_type(8)));
typedef float f32x4 __attribute__((ext_vector_type(4)));

#define GLOAD_LDS16(g, l)                                                      \
  __builtin_amdgcn_global_load_lds(                                            \
      (const __attribute__((address_space(1))) void*)(g),                      \
      (__attribute__((address_space(3))) void*)(l), 16, 0, 0)

// XCD-aware block relabel (proven round 3): group all blocks sharing an
// A-panel onto one XCD. Bijective since gridDim.y % 8 == 0.
__device__ inline void xcd_swizzle(int& bx, int& by) {
  int gx = gridDim.x, gy = gridDim.y;
  int h = blockIdx.x + gx * blockIdx.y;
  int c = h & 7, idx = h >> 3;
  bx = idx % gx;
  by = c * (gy >> 3) + idx / gx;
}

// ---------------------------------------------------------------------------
// Transpose x (B, DIM, T) -> xt (B*T, DIM) fp32 + split f16 (hi, lo)
// ---------------------------------------------------------------------------
__global__ __launch_bounds__(256) void transpose_xt(const float* __restrict__ x,
                                                    float* __restrict__ xt,
                                                    _Float16* __restrict__ xhi,
                                                    _Float16* __restrict__ xlo) {
  __shared__ float tile[32][33];
  int tx = threadIdx.x, ty = threadIdx.y;
  int b = blockIdx.z;
  int t0 = blockIdx.x * 32, c0 = blockIdx.y * 32;
  const float* xb = x + (size_t)b * DIM * TT;
#pragma unroll
  for (int j = 0; j < 32; j += 8)
    tile[ty + j][tx] = xb[(size_t)(c0 + ty + j) * TT + (t0 + tx)];
  __syncthreads();
#pragma unroll
  for (int j = 0; j < 32; j += 8) {
    float v = tile[tx][ty + j];
    size_t gi = ((size_t)b * TT + t0 + ty + j) * DIM + (c0 + tx);
    xt[gi] = v;
    _Float16 h = (_Float16)v;
    xhi[gi] = h;
    xlo[gi] = (_Float16)(v - (float)h);
  }
}

// ---------------------------------------------------------------------------
// Merged weight prep: dec_w0/dec_w1/fin_w -> f16; enc_w0/enc_w1 -> x64 split
// ---------------------------------------------------------------------------
__device__ inline void conv4(const float* __restrict__ in,
                             _Float16* __restrict__ o, int i) {
  float4 v = ((const float4*)in)[i];
  half4 hv;
  hv.x = (_Float16)v.x; hv.y = (_Float16)v.y;
  hv.z = (_Float16)v.z; hv.w = (_Float16)v.w;
  ((half4*)o)[i] = hv;
}

__device__ inline void split4(const float* __restrict__ in,
                              _Float16* __restrict__ hi,
                              _Float16* __restrict__ lo, int i, float scale) {
  float4 v = ((const float4*)in)[i];
  v.x *= scale; v.y *= scale; v.z *= scale; v.w *= scale;
  half4 hv, lv;
  hv.x = (_Float16)v.x; lv.x = (_Float16)(v.x - (float)hv.x);
  hv.y = (_Float16)v.y; lv.y = (_Float16)(v.y - (float)hv.y);
  hv.z = (_Float16)v.z; lv.z = (_Float16)(v.z - (float)hv.z);
  hv.w = (_Float16)v.w; lv.w = (_Float16)(v.w - (float)hv.w);
  ((half4*)hi)[i] = hv;
  ((half4*)lo)[i] = lv;
}

__global__ __launch_bounds__(256) void prep_weights(
    const float* __restrict__ dw0, const float* __restrict__ dw1,
    const float* __restrict__ fw, const float* __restrict__ ew0,
    const float* __restrict__ ew1, _Float16* __restrict__ w0h,
    _Float16* __restrict__ w1h, _Float16* __restrict__ wfh,
    _Float16* __restrict__ w0hi, _Float16* __restrict__ w0lo,
    _Float16* __restrict__ w1hi, _Float16* __restrict__ w1lo) {
  int b = blockIdx.x, t = threadIdx.x;
  if (b < 256) {                       // dec_w0: HID*DD/4 = 65536
    conv4(dw0, w0h, b * 256 + t);
  } else if (b < 1280) {               // dec_w1: HID*HID/4 = 262144
    conv4(dw1, w1h, (b - 256) * 256 + t);
  } else if (b < 1792) {               // fin_w: DIM*HID/4 = 131072
    conv4(fw, wfh, (b - 1280) * 256 + t);
  } else if (b < 2304) {               // enc_w0 split x64
    split4(ew0, w0hi, w0lo, (b - 1792) * 256 + t, 64.f);
  } else {                             // enc_w1 split x64
    split4(ew1, w1hi, w1lo, (b - 2304) * 256 + t, 64.f);
  }
}

// ---------------------------------------------------------------------------
// Wfold = blockdiag(cb_q) @ wo : NN GEMM. Tiny (1.1 GF).
// ---------------------------------------------------------------------------
__global__ __launch_bounds__(256) void fold_w(const float* __restrict__ cb,
                                              const float* __restrict__ wo,
                                              float* __restrict__ Wf) {
  __shared__ float As[8][128];
  __shared__ float Ws[8][128];
  const int tid = threadIdx.x;
  const int n0 = blockIdx.x * 128;
  const int m0 = blockIdx.y * 128;
  const int q = m0 >> 8;
  const int lr = tid >> 1, lk = (tid & 1) << 2;
  const float* Ap = cb + (size_t)q * CC * DD + (size_t)((m0 & 255) + lr) * DD + lk;
  const int br = tid >> 5, bc = (tid & 31) << 2;
  const float* Bp = wo + (size_t)(q * CC + br) * HID + n0 + bc;
  const int tm = (tid >> 4) << 3, tn = (tid & 15) << 3;

  float acc[8][8];
#pragma unroll
  for (int i = 0; i < 8; i++)
#pragma unroll
    for (int j = 0; j < 8; j++) acc[i][j] = 0.f;

  for (int kb = 0; kb < DD; kb += 8) {
    float4 av = *(const float4*)(Ap + kb);
    float4 bb = *(const float4*)(Bp + (size_t)kb * HID);
    __syncthreads();
    As[lk + 0][lr] = av.x; As[lk + 1][lr] = av.y;
    As[lk + 2][lr] = av.z; As[lk + 3][lr] = av.w;
    *(float4*)&Ws[br][bc] = bb;
    __syncthreads();
#pragma unroll
    for (int k = 0; k < 8; ++k) {
      float a[8], b[8];
      *(float4*)(a) = *(const float4*)(&As[k][tm]);
      *(float4*)(a + 4) = *(const float4*)(&As[k][tm + 4]);
      *(float4*)(b) = *(const float4*)(&Ws[k][tn]);
      *(float4*)(b + 4) = *(const float4*)(&Ws[k][tn + 4]);
#pragma unroll
      for (int i = 0; i < 8; i++)
#pragma unroll
        for (int j = 0; j < 8; j++) acc[i][j] = fmaf(a[i], b[j], acc[i][j]);
    }
  }
#pragma unroll
  for (int i = 0; i < 8; i++) {
    float* Cp = Wf + (size_t)(m0 + tm + i) * HID + (n0 + tn);
    float4 o;
    o.x = acc[i][0]; o.y = acc[i][1]; o.z = acc[i][2]; o.w = acc[i][3];
    *(float4*)Cp = o;
    o.x = acc[i][4]; o.y = acc[i][5]; o.z = acc[i][6]; o.w = acc[i][7];
    *(float4*)(Cp + 4) = o;
  }
}

// bfold[q*256+c] = sum_d cb[q,c,d] * bo[q*256+d]
__global__ __launch_bounds__(256) void fold_b(const float* __restrict__ cb,
                                              const float* __restrict__ bo,
                                              float* __restrict__ bf) {
  int q = blockIdx.x, c = threadIdx.x;
  const float* row = cb + ((size_t)q * CC + c) * DD;
  const float* b = bo + q * DD;
  float s = 0.f;
  for (int d = 0; d < DD; d++) s = fmaf(row[d], b[d], s);
  bf[q * CC + c] = s;
}

// ---------------------------------------------------------------------------
// Encoder split-f16 3-term MFMA NT GEMM, XCD-swizzled (proven round 2/3).
// BK=32 — the round-5 BK=64 variant regressed; reverted.
// ---------------------------------------------------------------------------
__global__ __launch_bounds__(256, 2) void hgemm3s_nt(
    const _Float16* __restrict__ Ahi, const _Float16* __restrict__ Alo,
    const _Float16* __restrict__ Whi, const _Float16* __restrict__ Wlo,
    const float* __restrict__ bias, float invsc, _Float16* __restrict__ Chi,
    _Float16* __restrict__ Clo, int ldc, int K, float* __restrict__ stats,
    int N) {
  __shared__ _Float16 Ah[4 * 128 * 8];
  __shared__ _Float16 Al[4 * 128 * 8];
  __shared__ _Float16 Bh[4 * 128 * 8];
  __shared__ _Float16 Bl[4 * 128 * 8];
  int BX, BY;
  xcd_swizzle(BX, BY);
  const int tid = threadIdx.x;
  const int l = tid & 63;
  const int w = tid >> 6;
  const int m0 = BY * 128, n0 = BX * 128;
  const int wrow = (w >> 1) * 64, wcol = (w & 1) * 64;

  const int s0 = tid, s1 = tid + 256;
  const int r0 = s0 & 127, kp0 = s0 >> 7;
  const int r1 = s1 & 127, kp1 = s1 >> 7;
  const size_t a0o = (size_t)(m0 + r0) * K + kp0 * 8;
  const size_t a1o = (size_t)(m0 + r1) * K + kp1 * 8;
  const size_t w0o = (size_t)(n0 + r0) * K + kp0 * 8;
  const size_t w1o = (size_t)(n0 + r1) * K + kp1 * 8;

  f32x4 acc[4][4] = {};

  for (int kb = 0; kb < K; kb += 32) {
    __syncthreads();
    GLOAD_LDS16(Ahi + a0o + kb, &Ah[s0 * 8]);
    GLOAD_LDS16(Ahi + a1o + kb, &Ah[s1 * 8]);
    GLOAD_LDS16(Alo + a0o + kb, &Al[s0 * 8]);
    GLOAD_LDS16(Alo + a1o + kb, &Al[s1 * 8]);
    GLOAD_LDS16(Whi + w0o + kb, &Bh[s0 * 8]);
    GLOAD_LDS16(Whi + w1o + kb, &Bh[s1 * 8]);
    GLOAD_LDS16(Wlo + w0o + kb, &Bl[s0 * 8]);
    GLOAD_LDS16(Wlo + w1o + kb, &Bl[s1 * 8]);
    __syncthreads();
    half8 ah[4], al[4], bh[4], bl[4];
#pragma unroll
    for (int i = 0; i < 4; i++) {
      const int idx = (((l >> 4) << 7) + wrow + i * 16 + (l & 15)) * 8;
      ah[i] = *(const half8*)&Ah[idx];
      al[i] = *(const half8*)&Al[idx];
    }
#pragma unroll
    for (int j = 0; j < 4; j++) {
      const int idx = (((l >> 4) << 7) + wcol + j * 16 + (l & 15)) * 8;
      bh[j] = *(const half8*)&Bh[idx];
      bl[j] = *(const half8*)&Bl[idx];
    }
#pragma unroll
    for (int i = 0; i < 4; i++)
#pragma unroll
      for (int j = 0; j < 4; j++) {
        acc[i][j] = __builtin_amdgcn_mfma_f32_16x16x32_f16(ah[i], bh[j],
                                                           acc[i][j], 0, 0, 0);
        acc[i][j] = __builtin_amdgcn_mfma_f32_16x16x32_f16(al[i], bh[j],
                                                           acc[i][j], 0, 0, 0);
        acc[i][j] = __builtin_amdgcn_mfma_f32_16x16x32_f16(ah[i], bl[j],
                                                           acc[i][j], 0, 0, 0);
      }
  }

#pragma unroll
  for (int j = 0; j < 4; j++) {
    const int col = n0 + wcol + j * 16 + (l & 15);
    const float bb = bias[col];
    float s1v = 0.f, s2v = 0.f;
#pragma unroll
    for (int i = 0; i < 4; i++) {
#pragma unroll
      for (int r = 0; r < 4; r++) {
        float v = fmaf(acc[i][j][r], invsc, bb);
        const int row = m0 + wrow + i * 16 + ((l >> 4) << 2) + r;
        _Float16 hv = (_Float16)v;
        Chi[(size_t)row * ldc + col] = hv;
        Clo[(size_t)row * ldc + col] = (_Float16)(v - (float)hv);
        s1v += v;
        s2v = fmaf(v, v, s2v);
      }
    }
    s1v += __shfl_xor(s1v, 16); s1v += __shfl_xor(s1v, 32);
    s2v += __shfl_xor(s2v, 16); s2v += __shfl_xor(s2v, 32);
    if (l < 16) {
      atomicAdd(&stats[col], s1v);
      atomicAdd(&stats[N + col], s2v);
    }
  }
}

// ---------------------------------------------------------------------------
// split-f16 3-term MFMA GEMM + dual argmax, XCD-swizzled (proven; no setprio
// — the round-5 variant regressed).
// ---------------------------------------------------------------------------
__global__ __launch_bounds__(512, 4) void hgemm3_wo_argmax(
    const _Float16* __restrict__ Ahi, const _Float16* __restrict__ Alo,
    const _Float16* __restrict__ Whi, const _Float16* __restrict__ Wlo,
    const float* __restrict__ bf, const float* __restrict__ u,
    const float* __restrict__ log_temps, float* __restrict__ out_idx,
    int* __restrict__ idx2) {
  __shared__ _Float16 Ahs[4 * 128 * 8];
  __shared__ _Float16 Als[4 * 128 * 8];
  __shared__ _Float16 Bhs[4 * 256 * 8];
  __shared__ _Float16 Bls[4 * 256 * 8];
  __shared__ float redv[2][128][4];
  __shared__ int   redi[2][128][4];
  int BX, BY;
  xcd_swizzle(BX, BY);
  const int tid = threadIdx.x;
  const int l = tid & 63;
  const int w = tid >> 6;
  const int q = BX;
  const int m0 = BY * 128;
  const int n0 = q * CC;
  const int wrow = (w >> 2) * 64, wcol = (w & 3) * 64;

  const int ar = tid & 127, akp = tid >> 7;
  const _Float16* Agh = Ahi + (size_t)(m0 + ar) * HID + akp * 8;
  const _Float16* Agl = Alo + (size_t)(m0 + ar) * HID + akp * 8;
  _Float16* Ahd = &Ahs[tid * 8];
  _Float16* Ald = &Als[tid * 8];
  const int s0 = tid, s1 = tid + 512;
  const int br0 = s0 & 255, bkp0 = s0 >> 8;
  const int br1 = s1 & 255, bkp1 = s1 >> 8;
  const _Float16* Bgh0 = Whi + (size_t)(n0 + br0) * HID + bkp0 * 8;
  const _Float16* Bgh1 = Whi + (size_t)(n0 + br1) * HID + bkp1 * 8;
  const _Float16* Bgl0 = Wlo + (size_t)(n0 + br0) * HID + bkp0 * 8;
  const _Float16* Bgl1 = Wlo + (size_t)(n0 + br1) * HID + bkp1 * 8;
  _Float16* Bhd0 = &Bhs[s0 * 8]; _Float16* Bhd1 = &Bhs[s1 * 8];
  _Float16* Bld0 = &Bls[s0 * 8]; _Float16* Bld1 = &Bls[s1 * 8];

  f32x4 acc[4][4] = {};

  for (int kb = 0; kb < HID; kb += 32) {
    __syncthreads();
    GLOAD_LDS16(Agh + kb, Ahd);
    GLOAD_LDS16(Agl + kb, Ald);
    GLOAD_LDS16(Bgh0 + kb, Bhd0);
    GLOAD_LDS16(Bgh1 + kb, Bhd1);
    GLOAD_LDS16(Bgl0 + kb, Bld0);
    GLOAD_LDS16(Bgl1 + kb, Bld1);
    __syncthreads();
    half8 ah[4], al[4], bh[4], bl[4];
#pragma unroll
    for (int i = 0; i < 4; i++) {
      const int idx = ((l >> 4) * 128 + wrow + i * 16 + (l & 15)) * 8;
      ah[i] = *(const half8*)&Ahs[idx];
      al[i] = *(const half8*)&Als[idx];
    }
#pragma unroll
    for (int j = 0; j < 4; j++) {
      const int idx = ((l >> 4) * 256 + wcol + j * 16 + (l & 15)) * 8;
      bh[j] = *(const half8*)&Bhs[idx];
      bl[j] = *(const half8*)&Bls[idx];
    }
#pragma unroll
    for (int i = 0; i < 4; i++)
#pragma unroll
      for (int j = 0; j < 4; j++) {
        acc[i][j] = __builtin_amdgcn_mfma_f32_16x16x32_f16(ah[i], bh[j],
                                                           acc[i][j], 0, 0, 0);
        acc[i][j] = __builtin_amdgcn_mfma_f32_16x16x32_f16(al[i], bh[j],
                                                           acc[i][j], 0, 0, 0);
        acc[i][j] = __builtin_amdgcn_mfma_f32_16x16x32_f16(ah[i], bl[j],
                                                           acc[i][j], 0, 0, 0);
      }
  }

  const float scale = expf(-log_temps[q]);
  float bcol[4];
#pragma unroll
  for (int j = 0; j < 4; j++) bcol[j] = bf[n0 + wcol + j * 16 + (l & 15)];

#pragma unroll
  for (int i = 0; i < 4; i++) {
#pragma unroll
    for (int r = 0; r < 4; r++) {
      const int rloc = wrow + i * 16 + ((l >> 4) << 2) + r;
      const int row = m0 + rloc;
      float bvv = -INFINITY; int bi = 0;
      float gv = -INFINITY; int gi = 0;
#pragma unroll
      for (int j = 0; j < 4; j++) {
        const int c = wcol + j * 16 + (l & 15);
        float v = acc[i][j][r] + bcol[j];
        if (v > bvv) { bvv = v; bi = c; }
        float uu = u[(size_t)row * (QQ * CC) + n0 + c];
        float uc = fminf(fmaxf(uu, 1e-9f), 1.0f);
        float g = -logf(-logf(uc) + 1e-20f);
        float y = fmaf(v, scale, g);
        if (y > gv) { gv = y; gi = c; }
      }
#pragma unroll
      for (int off = 1; off < 16; off <<= 1) {
        float b2 = __shfl_xor(bvv, off); int bi2 = __shfl_xor(bi, off);
        if (b2 > bvv || (b2 == bvv && bi2 < bi)) { bvv = b2; bi = bi2; }
        float g2 = __shfl_xor(gv, off); int gi2 = __shfl_xor(gi, off);
        if (g2 > gv || (g2 == gv && gi2 < gi)) { gv = g2; gi = gi2; }
      }
      if ((l & 15) == 0) {
        redv[0][rloc][w & 3] = bvv; redi[0][rloc][w & 3] = bi;
        redv[1][rloc][w & 3] = gv;  redi[1][rloc][w & 3] = gi;
      }
    }
  }
  __syncthreads();
  if (tid < 128) {
    float bv = redv[0][tid][0]; int bi = redi[0][tid][0];
    float gv = redv[1][tid][0]; int gi = redi[1][tid][0];
#pragma unroll
    for (int c = 1; c < 4; c++) {
      float v = redv[0][tid][c];
      if (v > bv) { bv = v; bi = redi[0][tid][c]; }
      float v2 = redv[1][tid][c];
      if (v2 > gv) { gv = v2; gi = redi[1][tid][c]; }
    }
    const int row = m0 + tid;
    out_idx[(size_t)row * QQ + q] = (float)bi;
    idx2[(size_t)row * QQ + q] = gi;
  }
}

// ---------------------------------------------------------------------------
// FP16 MFMA NT GEMM, f16 output + fused col stats (decoder layers)
// ---------------------------------------------------------------------------
__global__ __launch_bounds__(256, 2) void hgemm_ntf16(
    const _Float16* __restrict__ A, const _Float16* __restrict__ W,
    const float* __restrict__ bias, _Float16* __restrict__ C, int ldc, int K,
    float* __restrict__ stats, int N) {
  __shared__ _Float16 Al[4 * 128 * 8];
  __shared__ _Float16 Bl[4 * 128 * 8];
  int BX, BY;
  xcd_swizzle(BX, BY);
  const int tid = threadIdx.x;
  const int l = tid & 63;
  const int w = tid >> 6;
  const int m0 = BY * 128, n0 = BX * 128;
  const int wrow = (w >> 1) * 64, wcol = (w & 1) * 64;

  const int s0 = tid, s1 = tid + 256;
  const int r0 = s0 & 127, kp0 = s0 >> 7;
  const int r1 = s1 & 127, kp1 = s1 >> 7;
  const _Float16* Ag0 = A + (size_t)(m0 + r0) * K + kp0 * 8;
  const _Float16* Ag1 = A + (size_t)(m0 + r1) * K + kp1 * 8;
  const _Float16* Wg0 = W + (size_t)(n0 + r0) * K + kp0 * 8;
  const _Float16* Wg1 = W + (size_t)(n0 + r1) * K + kp1 * 8;
  _Float16* Al0 = &Al[s0 * 8]; _Float16* Al1 = &Al[s1 * 8];
  _Float16* Bl0 = &Bl[s0 * 8]; _Float16* Bl1 = &Bl[s1 * 8];

  f32x4 acc[4][4] = {};

  for (int kb = 0; kb < K; kb += 32) {
    __syncthreads();
    GLOAD_LDS16(Ag0 + kb, Al0);
    GLOAD_LDS16(Ag1 + kb, Al1);
    GLOAD_LDS16(Wg0 + kb, Bl0);
    GLOAD_LDS16(Wg1 + kb, Bl1);
    __syncthreads();
    half8 af[4], bf[4];
#pragma unroll
    for (int i = 0; i < 4; i++)
      af[i] = *(const half8*)&Al[(((l >> 4) << 7) + wrow + i * 16 + (l & 15)) * 8];
#pragma unroll
    for (int j = 0; j < 4; j++)
      bf[j] = *(const half8*)&Bl[(((l >> 4) << 7) + wcol + j * 16 + (l & 15)) * 8];
#pragma unroll
    for (int i = 0; i < 4; i++)
#pragma unroll
      for (int j = 0; j < 4; j++)
        acc[i][j] = __builtin_amdgcn_mfma_f32_16x16x32_f16(af[i], bf[j],
                                                           acc[i][j], 0, 0, 0);
  }

#pragma unroll
  for (int j = 0; j < 4; j++) {
    const int col = n0 + wcol + j * 16 + (l & 15);
    const float bb = bias[col];
    float s1v = 0.f, s2v = 0.f;
#pragma unroll
    for (int i = 0; i < 4; i++) {
#pragma unroll
      for (int r = 0; r < 4; r++) {
        float v = acc[i][j][r] + bb;
        const int row = m0 + wrow + i * 16 + ((l >> 4) << 2) + r;
        C[(size_t)row * ldc + col] = (_Float16)v;
        s1v += v;
        s2v = fmaf(v, v, s2v);
      }
    }
    s1v += __shfl_xor(s1v, 16); s1v += __shfl_xor(s1v, 32);
    s2v += __shfl_xor(s2v, 16); s2v += __shfl_xor(s2v, 32);
    if (l < 16) {
      atomicAdd(&stats[col], s1v);
      atomicAdd(&stats[N + col], s2v);
    }
  }
}

// ---------------------------------------------------------------------------
// Final FP16 MFMA NT GEMM: fp32 output + fused commit loss vs xt
// ---------------------------------------------------------------------------
__global__ __launch_bounds__(256, 2) void hgemm_nt_loss(
    const _Float16* __restrict__ A, const _Float16* __restrict__ W,
    const float* __restrict__ bias, float* __restrict__ C, int ldc, int K,
    const float* __restrict__ xt, float* __restrict__ out_loss) {
  __shared__ _Float16 Al[4 * 128 * 8];
  __shared__ _Float16 Bl[4 * 128 * 8];
  int BX, BY;
  xcd_swizzle(BX, BY);
  const int tid = threadIdx.x;
  const int l = tid & 63;
  const int w = tid >> 6;
  const int m0 = BY * 128, n0 = BX * 128;
  const int wrow = (w >> 1) * 64, wcol = (w & 1) * 64;

  const int s0 = tid, s1 = tid + 256;
  const int r0 = s0 & 127, kp0 = s0 >> 7;
  const int r1 = s1 & 127, kp1 = s1 >> 7;
  const _Float16* Ag0 = A + (size_t)(m0 + r0) * K + kp0 * 8;
  const _Float16* Ag1 = A + (size_t)(m0 + r1) * K + kp1 * 8;
  const _Float16* Wg0 = W + (size_t)(n0 + r0) * K + kp0 * 8;
  const _Float16* Wg1 = W + (size_t)(n0 + r1) * K + kp1 * 8;
  _Float16* Al0 = &Al[s0 * 8]; _Float16* Al1 = &Al[s1 * 8];
  _Float16* Bl0 = &Bl[s0 * 8]; _Float16* Bl1 = &Bl[s1 * 8];

  f32x4 acc[4][4] = {};

  for (int kb = 0; kb < K; kb += 32) {
    __syncthreads();
    GLOAD_LDS16(Ag0 + kb, Al0);
    GLOAD_LDS16(Ag1 + kb, Al1);
    GLOAD_LDS16(Wg0 + kb, Bl0);
    GLOAD_LDS16(Wg1 + kb, Bl1);
    __syncthreads();
    half8 af[4], bf[4];
#pragma unroll
    for (int i = 0; i < 4; i++)
      af[i] = *(const half8*)&Al[(((l >> 4) << 7) + wrow + i * 16 + (l & 15)) * 8];
#pragma unroll
    for (int j = 0; j < 4; j++)
      bf[j] = *(const half8*)&Bl[(((l >> 4) << 7) + wcol + j * 16 + (l & 15)) * 8];
#pragma unroll
    for (int i = 0; i < 4; i++)
#pragma unroll
      for (int j = 0; j < 4; j++)
        acc[i][j] = __builtin_amdgcn_mfma_f32_16x16x32_f16(af[i], bf[j],
                                                           acc[i][j], 0, 0, 0);
  }

  float ls = 0.f;
#pragma unroll
  for (int j = 0; j < 4; j++) {
    const int col = n0 + wcol + j * 16 + (l & 15);
    const float bb = bias[col];
#pragma unroll
    for (int i = 0; i < 4; i++) {
#pragma unroll
      for (int r = 0; r < 4; r++) {
        float v = acc[i][j][r] + bb;
        const int row = m0 + wrow + i * 16 + ((l >> 4) << 2) + r;
        C[(size_t)row * ldc + col] = v;
        float d = v - xt[(size_t)row * ldc + col];
        ls = fmaf(d, d, ls);
      }
    }
  }
#pragma unroll
  for (int off = 32; off > 0; off >>= 1) ls += __shfl_xor(ls, off);
  if (l == 0)
    atomicAdd(out_loss, ls * (1.0f / ((float)BT * (float)DIM)));
}

// ---------------------------------------------------------------------------
// BatchNorm helpers
// ---------------------------------------------------------------------------
__global__ __launch_bounds__(256) void bn_finalize(const float* __restrict__ sums,
                                                   const float* __restrict__ gamma,
                                                   const float* __restrict__ beta,
                                                   float* __restrict__ ss, int N) {
  int n = blockIdx.x * 256 + threadIdx.x;
  if (n >= N) return;
  const float invM = 1.0f / (float)BT;
  float mean = sums[n] * invM;
  float var = sums[N + n] * invM - mean * mean;
  float sc = gamma[n] / sqrtf(var + EPSB);
  ss[n] = sc;
  ss[N + n] = beta[n] - mean * sc;
}

// in-place BN (+relu) on a split (hi, lo) f16 pair
__global__ __launch_bounds__(256) void bn_resplit(_Float16* __restrict__ hi,
                                                  _Float16* __restrict__ lo,
                                                  const float* __restrict__ ss,
                                                  int nmask, int N, long n4,
                                                  int relu) {
  long stride = (long)gridDim.x * 256;
  for (long i = (long)blockIdx.x * 256 + threadIdx.x; i < n4; i += stride) {
    int col = (int)((i << 2) & nmask);
    half4 h = ((half4*)hi)[i];
    half4 L = ((half4*)lo)[i];
    float4 sc = *(const float4*)(ss + col);
    float4 sh = *(const float4*)(ss + N + col);
    float vx = fmaf((float)h.x + (float)L.x, sc.x, sh.x);
    float vy = fmaf((float)h.y + (float)L.y, sc.y, sh.y);
    float vz = fmaf((float)h.z + (float)L.z, sc.z, sh.z);
    float vw = fmaf((float)h.w + (float)L.w, sc.w, sh.w);
    if (relu) {
      vx = fmaxf(vx, 0.f); vy = fmaxf(vy, 0.f);
      vz = fmaxf(vz, 0.f); vw = fmaxf(vw, 0.f);
    }
    half4 hv, lv;
    hv.x = (_Float16)vx; lv.x = (_Float16)(vx - (float)hv.x);
    hv.y = (_Float16)vy; lv.y = (_Float16)(vy - (float)hv.y);
    hv.z = (_Float16)vz; lv.z = (_Float16)(vz - (float)hv.z);
    hv.w = (_Float16)vw; lv.w = (_Float16)(vw - (float)hv.w);
    ((half4*)hi)[i] = hv;
    ((half4*)lo)[i] = lv;
  }
}

// in-place BN (+relu) on an f16 buffer
__global__ __launch_bounds__(256) void bnf16_inplace(_Float16* __restrict__ h,
                                                     const float* __restrict__ ss,
                                                     int nmask, int N, long n4,
                                                     int relu) {
  long stride = (long)gridDim.x * 256;
  for (long i = (long)blockIdx.x * 256 + threadIdx.x; i < n4; i += stride) {
    int col = (int)((i << 2) & nmask);
    half4 v = ((half4*)h)[i];
    float4 sc = *(const float4*)(ss + col);
    float4 sh = *(const float4*)(ss + N + col);
    float vx = fmaf((float)v.x, sc.x, sh.x);
    float vy = fmaf((float)v.y, sc.y, sh.y);
    float vz = fmaf((float)v.z, sc.z, sh.z);
    float vw = fmaf((float)v.w, sc.w, sh.w);
    if (relu) {
      vx = fmaxf(vx, 0.f); vy = fmaxf(vy, 0.f);
      vz = fmaxf(vz, 0.f); vw = fmaxf(vw, 0.f);
    }
    half4 o;
    o.x = (_Float16)vx; o.y = (_Float16)vy;
    o.z = (_Float16)vz; o.w = (_Float16)vw;
    ((half4*)h)[i] = o;
  }
}

// fp32 h -> f16 out with BN scale/shift (+optional relu)
__global__ __launch_bounds__(256) void bn_apply_f16(const float* __restrict__ h,
                                                    const float* __restrict__ ss,
                                                    int nmask, int N, long n4,
                                                    int relu,
                                                    _Float16* __restrict__ o) {
  long stride = (long)gridDim.x * 256;
  for (long i = (long)blockIdx.x * 256 + threadIdx.x; i < n4; i += stride) {
    int col = (int)((i << 2) & nmask);
    float4 v = ((const float4*)h)[i];
    float4 sc = *(const float4*)(ss + col);
    float4 sh = *(const float4*)(ss + N + col);
    v.x = fmaf(v.x, sc.x, sh.x); v.y = fmaf(v.y, sc.y, sh.y);
    v.z = fmaf(v.z, sc.z, sh.z); v.w = fmaf(v.w, sc.w, sh.w);
    if (relu) {
      v.x = fmaxf(v.x, 0.f); v.y = fmaxf(v.y, 0.f);
      v.z = fmaxf(v.z, 0.f); v.w = fmaxf(v.w, 0.f);
    }
    half4 hv;
    hv.x = (_Float16)v.x; hv.y = (_Float16)v.y;
    hv.z = (_Float16)v.z; hv.w = (_Float16)v.w;
    ((half4*)o)[i] = hv;
  }
}

// fp32 -> split (hi, lo) f16 with optional pre-scale (used for Wf)
__global__ __launch_bounds__(256) void conv_split_s(const float* __restrict__ in,
                                                    _Float16* __restrict__ hi,
                                                    _Float16* __restrict__ lo,
                                                    int n4, float scale) {
  int i = blockIdx.x * 256 + threadIdx.x;
  if (i >= n4) return;
  split4(in, hi, lo, i, scale);
}

// ---------------------------------------------------------------------------
// emb[bt, d] = sum_q codebook[q, idx2[bt,q], d]  + fused column stats.
// ---------------------------------------------------------------------------
__global__ __launch_bounds__(256) void emb_gather_stats(
    const float* __restrict__ cb, const int* __restrict__ idx2,
    float* __restrict__ emb, float* __restrict__ sums) {
  __shared__ int k[64][8];
  const int r0 = blockIdx.x * 64;
  const int tid = threadIdx.x;
  for (int t = tid; t < 64 * QQ; t += 256)
    k[t >> 3][t & 7] = idx2[(size_t)(r0 + (t >> 3)) * QQ + (t & 7)];
  __syncthreads();
  const int d = tid;
  float s1 = 0.f, s2 = 0.f;
  for (int rr = 0; rr < 64; rr++) {
    float s = 0.f;
#pragma unroll
    for (int q = 0; q < QQ; q++)
      s += cb[((size_t)(q * CC + k[rr][q])) * DD + d];
    emb[(size_t)(r0 + rr) * DD + d] = s;
    s1 += s;
    s2 = fmaf(s, s, s2);
  }
  atomicAdd(&sums[d], s1);
  atomicAdd(&sums[DD + d], s2);
}

// ---------------------------------------------------------------------------
// Workspace layout (float offsets) — unchanged.
// ---------------------------------------------------------------------------
static const size_t OF_XT = 0;
static const size_t OF_R1 = OF_XT + (size_t)BT * DIM;
static const size_t OF_R2 = OF_R1 + (size_t)BT * HID;
static const size_t OF_WF = OF_R2 + (size_t)BT * HID;
static const size_t OF_BF = OF_WF + (size_t)2048 * HID;
static const size_t OF_EMBH = OF_BF + 2048;
static const size_t OF_HB = OF_EMBH + (size_t)BT * DD / 2;
static const size_t OF_W0H = OF_HB + (size_t)BT * HID / 2;
static const size_t OF_W1H = OF_W0H + (size_t)HID * DD / 2;
static const size_t OF_WFH = OF_W1H + (size_t)HID * HID / 2;
static const size_t OF_I2 = OF_WFH + (size_t)DIM * HID / 2;
static const size_t OF_ST = OF_I2 + (size_t)BT * QQ;
static const size_t OF_SS0 = OF_ST + 4096;
static const size_t OF_SS1 = OF_SS0 + 2048;
static const size_t OF_SSD = OF_SS1 + 2048;
static const size_t OF_SD0 = OF_SSD + 1024;
static const size_t OF_SD1 = OF_SD0 + 2048;

extern "C" void kernel_launch(void* const* d_in, const int* in_sizes, int n_in,
                              void* d_out, int out_size, void* d_ws, size_t ws_size,
                              hipStream_t stream) {
  const float* x        = (const float*)d_in[0];
  const float* u        = (const float*)d_in[1];
  const float* codebook = (const float*)d_in[2];
  const float* log_temps= (const float*)d_in[3];
  const float* enc_w0   = (const float*)d_in[4];
  const float* enc_b0   = (const float*)d_in[5];
  const float* enc_g0   = (const float*)d_in[6];
  const float* enc_be0  = (const float*)d_in[7];
  const float* enc_w1   = (const float*)d_in[8];
  const float* enc_b1   = (const float*)d_in[9];
  const float* enc_g1   = (const float*)d_in[10];
  const float* enc_be1  = (const float*)d_in[11];
  const float* enc_wo   = (const float*)d_in[12];
  const float* enc_bo   = (const float*)d_in[13];
  const float* dec_g    = (const float*)d_in[14];
  const float* dec_be   = (const float*)d_in[15];
  const float* dec_w0   = (const float*)d_in[16];
  const float* dec_b0   = (const float*)d_in[17];
  const float* dec_g0   = (const float*)d_in[18];
  const float* dec_be0  = (const float*)d_in[19];
  const float* dec_w1   = (const float*)d_in[20];
  const float* dec_b1   = (const float*)d_in[21];
  const float* dec_g1   = (const float*)d_in[22];
  const float* dec_be1  = (const float*)d_in[23];
  const float* fin_w    = (const float*)d_in[24];
  const float* fin_b    = (const float*)d_in[25];

  float* ws = (float*)d_ws;
  float* xt = ws + OF_XT;
  float* R1 = ws + OF_R1;
  float* Wf = ws + OF_WF;
  float* bfold = ws + OF_BF;
  _Float16* embh = (_Float16*)(ws + OF_EMBH);
  _Float16* w0h = (_Float16*)(ws + OF_W0H);
  _Float16* w1h = (_Float16*)(ws + OF_W1H);
  _Float16* wfh = (_Float16*)(ws + OF_WFH);
  int* idx2 = (int*)(ws + OF_I2);
  float* st = ws + OF_ST;
  float* ss0 = ws + OF_SS0;
  float* ss1 = ws + OF_SS1;
  float* ssd = ws + OF_SSD;
  float* sd0 = ws + OF_SD0;
  float* sd1 = ws + OF_SD1;

  // aliased split / f16 buffers (lifetimes verified rounds 2-4)
  _Float16* xthi = (_Float16*)(ws + OF_R2);
  _Float16* xtlo = (_Float16*)(ws + OF_R2 + (size_t)BT * DIM / 2);
  _Float16* w0hi = (_Float16*)(ws + OF_R2 + (size_t)BT * DIM);
  _Float16* w0lo = (_Float16*)(ws + OF_R2 + (size_t)BT * DIM + (size_t)HID * DIM / 2);
  _Float16* w1hi = (_Float16*)(ws + OF_R2 + (size_t)BT * DIM + (size_t)HID * DIM);
  _Float16* w1lo = (_Float16*)(ws + OF_R2 + (size_t)BT * DIM + (size_t)HID * DIM +
                               (size_t)HID * HID / 2);
  _Float16* r1hi = (_Float16*)(ws + OF_R1);
  _Float16* r1lo = (_Float16*)(ws + OF_R1 + (size_t)BT * HID / 2);
  _Float16* r2hi = (_Float16*)(ws + OF_HB);
  _Float16* r2lo = (_Float16*)(ws + OF_R2);
  _Float16* wfhi = (_Float16*)(ws + OF_R1);
  _Float16* wflo = (_Float16*)(ws + OF_R1 + (size_t)2048 * HID / 2);
  _Float16* h16a = (_Float16*)(ws + OF_R2);
  _Float16* h16b = (_Float16*)(ws + OF_R2 + (size_t)BT * HID / 2);

  float* out = (float*)d_out;
  float* out_idx = out + (size_t)BT * DIM;
  float* out_loss = out + (size_t)BT * DIM + (size_t)BT * QQ;

  hipMemsetAsync(out_loss, 0, sizeof(float), stream);

  // weight prep (merged) + codebook folding
  prep_weights<<<dim3(3328), 256, 0, stream>>>(
      dec_w0, dec_w1, fin_w, enc_w0, enc_w1, w0h, w1h, wfh, w0hi, w0lo, w1hi,
      w1lo);
  fold_w<<<dim3(HID / 128, 2048 / 128), 256, 0, stream>>>(codebook, enc_wo, Wf);
  fold_b<<<dim3(QQ), 256, 0, stream>>>(codebook, enc_bo, bfold);

  // 1. transpose (+ split f16 copies of xt)
  transpose_xt<<<dim3(TT / 32, DIM / 32, BB), dim3(32, 8), 0, stream>>>(
      x, xt, xthi, xtlo);

  // 2. enc0: r1 = xt @ enc_w0^T + b0 (split MFMA, stats fused); BN in place
  hipMemsetAsync(st, 0, 2 * HID * sizeof(float), stream);
  hgemm3s_nt<<<dim3(HID / 128, BT / 128), 256, 0, stream>>>(
      xthi, xtlo, w0hi, w0lo, enc_b0, 1.f / 64.f, r1hi, r1lo, HID, DIM, st, HID);
  bn_finalize<<<dim3(4), 256, 0, stream>>>(st, enc_g0, enc_be0, ss0, HID);
  bn_resplit<<<dim3(2048), 256, 0, stream>>>(r1hi, r1lo, ss0, HID - 1, HID,
                                             (long)BT * HID / 4, 1);

  // 3. enc1: r2 = r1 @ enc_w1^T + b1 (split MFMA, stats fused); BN in place
  hipMemsetAsync(st, 0, 2 * HID * sizeof(float), stream);
  hgemm3s_nt<<<dim3(HID / 128, BT / 128), 256, 0, stream>>>(
      r1hi, r1lo, w1hi, w1lo, enc_b1, 1.f / 64.f, r2hi, r2lo, HID, HID, st, HID);
  conv_split_s<<<dim3(2048 * HID / 4 / 256), 256, 0, stream>>>(
      Wf, wfhi, wflo, 2048 * HID / 4, 1.f);
  bn_finalize<<<dim3(4), 256, 0, stream>>>(st, enc_g1, enc_be1, ss1, HID);
  bn_resplit<<<dim3(2048), 256, 0, stream>>>(r2hi, r2lo, ss1, HID - 1, HID,
                                             (long)BT * HID / 4, 1);

  // 4. split-f16 MFMA wo-GEMM + argmax epilogue
  hgemm3_wo_argmax<<<dim3(QQ, BT / 128), 512, 0, stream>>>(
      r2hi, r2lo, wfhi, wflo, bfold, u, log_temps, out_idx, idx2);

  // 5. emb gather (+fused col stats) + BN -> f16
  hipMemsetAsync(st, 0, 2 * DD * sizeof(float), stream);
  emb_gather_stats<<<dim3(BT / 64), 256, 0, stream>>>(codebook, idx2, R1, st);
  bn_finalize<<<dim3(1), 256, 0, stream>>>(st, dec_g, dec_be, ssd, DD);
  bn_apply_f16<<<dim3(2048), 256, 0, stream>>>(R1, ssd, DD - 1, DD,
                                               (long)BT * DD / 4, 0, embh);

  // 6. decoder FFN in f16 MFMA (f16 output + in-place BN)
  hipMemsetAsync(st, 0, 2 * HID * sizeof(float), stream);
  hgemm_ntf16<<<dim3(HID / 128, BT / 128), 256, 0, stream>>>(
      embh, w0h, dec_b0, h16a, HID, DD, st, HID);
  bn_finalize<<<dim3(4), 256, 0, stream>>>(st, dec_g0, dec_be0, sd0, HID);
  bnf16_inplace<<<dim3(2048), 256, 0, stream>>>(h16a, sd0, HID - 1, HID,
                                                (long)BT * HID / 4, 1);

  hipMemsetAsync(st, 0, 2 * HID * sizeof(float), stream);
  hgemm_ntf16<<<dim3(HID / 128, BT / 128), 256, 0, stream>>>(
      h16a, w1h, dec_b1, h16b, HID, HID, st, HID);
  bn_finalize<<<dim3(4), 256, 0, stream>>>(st, dec_g1, dec_be1, sd1, HID);
  bnf16_inplace<<<dim3(2048), 256, 0, stream>>>(h16b, sd1, HID - 1, HID,
                                                (long)BT * HID / 4, 1);

  // 7. x_reco = h @ fin_w^T + fin_b  (+fused commit loss vs xt)
  hgemm_nt_loss<<<dim3(DIM / 128, BT / 128), 256, 0, stream>>>(
      h16b, wfh, fin_b, out, DIM, HID, xt, out_loss);
}

// Round 7
// 1163.251 us; speedup vs baseline: 1.1659x; 1.0150x over previous
//
#include <hip/hip_runtime.h>
#include <math.h>

#define BB   32
#define TT   512
#define DIM  512
#define HID  1024
#define QQ   8
#define CC   256
#define DD   256
#define BT   16384
#define EPSB 1e-5f

typedef _Float16 half4 __attribute__((ext_vector_type(4)));
typedef _Float16 half8 __attribute__((ext_vector_type(8)));
typedef float f32x4 __attribute__((ext_vector_type(4)));

#define GLOAD_LDS16(g, l)                                                      \
  __builtin_amdgcn_global_load_lds(                                            \
      (const __attribute__((address_space(1))) void*)(g),                      \
      (__attribute__((address_space(3))) void*)(l), 16, 0, 0)

// counted-vmcnt sync primitives (T3/T4): raw barrier, no implicit vmcnt(0)
#define S_BARRIER() asm volatile("s_barrier" ::: "memory")
#define S_VMCNT8()  asm volatile("s_waitcnt vmcnt(8)" ::: "memory")
#define S_VMCNT4()  asm volatile("s_waitcnt vmcnt(4)" ::: "memory")
#define S_VMCNT0()  asm volatile("s_waitcnt vmcnt(0)" ::: "memory")

// XCD-aware block relabel (proven round 3): group all blocks sharing an
// A-panel onto one XCD. Bijective since gridDim.y % 8 == 0.
__device__ inline void xcd_swizzle(int& bx, int& by) {
  int gx = gridDim.x, gy = gridDim.y;
  int h = blockIdx.x + gx * blockIdx.y;
  int c = h & 7, idx = h >> 3;
  bx = idx % gx;
  by = c * (gy >> 3) + idx / gx;
}

// ---------------------------------------------------------------------------
// Transpose x (B, DIM, T) -> xt (B*T, DIM) fp32 + split f16 (hi, lo)
// ---------------------------------------------------------------------------
__global__ __launch_bounds__(256) void transpose_xt(const float* __restrict__ x,
                                                    float* __restrict__ xt,
                                                    _Float16* __restrict__ xhi,
                                                    _Float16* __restrict__ xlo) {
  __shared__ float tile[32][33];
  int tx = threadIdx.x, ty = threadIdx.y;
  int b = blockIdx.z;
  int t0 = blockIdx.x * 32, c0 = blockIdx.y * 32;
  const float* xb = x + (size_t)b * DIM * TT;
#pragma unroll
  for (int j = 0; j < 32; j += 8)
    tile[ty + j][tx] = xb[(size_t)(c0 + ty + j) * TT + (t0 + tx)];
  __syncthreads();
#pragma unroll
  for (int j = 0; j < 32; j += 8) {
    float v = tile[tx][ty + j];
    size_t gi = ((size_t)b * TT + t0 + ty + j) * DIM + (c0 + tx);
    xt[gi] = v;
    _Float16 h = (_Float16)v;
    xhi[gi] = h;
    xlo[gi] = (_Float16)(v - (float)h);
  }
}

// ---------------------------------------------------------------------------
// Merged weight prep: dec_w0/dec_w1/fin_w -> f16; enc_w0/enc_w1 -> x64 split
// ---------------------------------------------------------------------------
__device__ inline void conv4(const float* __restrict__ in,
                             _Float16* __restrict__ o, int i) {
  float4 v = ((const float4*)in)[i];
  half4 hv;
  hv.x = (_Float16)v.x; hv.y = (_Float16)v.y;
  hv.z = (_Float16)v.z; hv.w = (_Float16)v.w;
  ((half4*)o)[i] = hv;
}

__device__ inline void split4(const float* __restrict__ in,
                              _Float16* __restrict__ hi,
                              _Float16* __restrict__ lo, int i, float scale) {
  float4 v = ((const float4*)in)[i];
  v.x *= scale; v.y *= scale; v.z *= scale; v.w *= scale;
  half4 hv, lv;
  hv.x = (_Float16)v.x; lv.x = (_Float16)(v.x - (float)hv.x);
  hv.y = (_Float16)v.y; lv.y = (_Float16)(v.y - (float)hv.y);
  hv.z = (_Float16)v.z; lv.z = (_Float16)(v.z - (float)hv.z);
  hv.w = (_Float16)v.w; lv.w = (_Float16)(v.w - (float)hv.w);
  ((half4*)hi)[i] = hv;
  ((half4*)lo)[i] = lv;
}

__global__ __launch_bounds__(256) void prep_weights(
    const float* __restrict__ dw0, const float* __restrict__ dw1,
    const float* __restrict__ fw, const float* __restrict__ ew0,
    const float* __restrict__ ew1, _Float16* __restrict__ w0h,
    _Float16* __restrict__ w1h, _Float16* __restrict__ wfh,
    _Float16* __restrict__ w0hi, _Float16* __restrict__ w0lo,
    _Float16* __restrict__ w1hi, _Float16* __restrict__ w1lo) {
  int b = blockIdx.x, t = threadIdx.x;
  if (b < 256) {                       // dec_w0: HID*DD/4 = 65536
    conv4(dw0, w0h, b * 256 + t);
  } else if (b < 1280) {               // dec_w1: HID*HID/4 = 262144
    conv4(dw1, w1h, (b - 256) * 256 + t);
  } else if (b < 1792) {               // fin_w: DIM*HID/4 = 131072
    conv4(fw, wfh, (b - 1280) * 256 + t);
  } else if (b < 2304) {               // enc_w0 split x64
    split4(ew0, w0hi, w0lo, (b - 1792) * 256 + t, 64.f);
  } else {                             // enc_w1 split x64
    split4(ew1, w1hi, w1lo, (b - 2304) * 256 + t, 64.f);
  }
}

// ---------------------------------------------------------------------------
// Wfold = blockdiag(cb_q) @ wo : NN GEMM. Tiny (1.1 GF).
// ---------------------------------------------------------------------------
__global__ __launch_bounds__(256) void fold_w(const float* __restrict__ cb,
                                              const float* __restrict__ wo,
                                              float* __restrict__ Wf) {
  __shared__ float As[8][128];
  __shared__ float Ws[8][128];
  const int tid = threadIdx.x;
  const int n0 = blockIdx.x * 128;
  const int m0 = blockIdx.y * 128;
  const int q = m0 >> 8;
  const int lr = tid >> 1, lk = (tid & 1) << 2;
  const float* Ap = cb + (size_t)q * CC * DD + (size_t)((m0 & 255) + lr) * DD + lk;
  const int br = tid >> 5, bc = (tid & 31) << 2;
  const float* Bp = wo + (size_t)(q * CC + br) * HID + n0 + bc;
  const int tm = (tid >> 4) << 3, tn = (tid & 15) << 3;

  float acc[8][8];
#pragma unroll
  for (int i = 0; i < 8; i++)
#pragma unroll
    for (int j = 0; j < 8; j++) acc[i][j] = 0.f;

  for (int kb = 0; kb < DD; kb += 8) {
    float4 av = *(const float4*)(Ap + kb);
    float4 bb = *(const float4*)(Bp + (size_t)kb * HID);
    __syncthreads();
    As[lk + 0][lr] = av.x; As[lk + 1][lr] = av.y;
    As[lk + 2][lr] = av.z; As[lk + 3][lr] = av.w;
    *(float4*)&Ws[br][bc] = bb;
    __syncthreads();
#pragma unroll
    for (int k = 0; k < 8; ++k) {
      float a[8], b[8];
      *(float4*)(a) = *(const float4*)(&As[k][tm]);
      *(float4*)(a + 4) = *(const float4*)(&As[k][tm + 4]);
      *(float4*)(b) = *(const float4*)(&Ws[k][tn]);
      *(float4*)(b + 4) = *(const float4*)(&Ws[k][tn + 4]);
#pragma unroll
      for (int i = 0; i < 8; i++)
#pragma unroll
        for (int j = 0; j < 8; j++) acc[i][j] = fmaf(a[i], b[j], acc[i][j]);
    }
  }
#pragma unroll
  for (int i = 0; i < 8; i++) {
    float* Cp = Wf + (size_t)(m0 + tm + i) * HID + (n0 + tn);
    float4 o;
    o.x = acc[i][0]; o.y = acc[i][1]; o.z = acc[i][2]; o.w = acc[i][3];
    *(float4*)Cp = o;
    o.x = acc[i][4]; o.y = acc[i][5]; o.z = acc[i][6]; o.w = acc[i][7];
    *(float4*)(Cp + 4) = o;
  }
}

// bfold[q*256+c] = sum_d cb[q,c,d] * bo[q*256+d]
__global__ __launch_bounds__(256) void fold_b(const float* __restrict__ cb,
                                              const float* __restrict__ bo,
                                              float* __restrict__ bf) {
  int q = blockIdx.x, c = threadIdx.x;
  const float* row = cb + ((size_t)q * CC + c) * DD;
  const float* b = bo + q * DD;
  float s = 0.f;
  for (int d = 0; d < DD; d++) s = fmaf(row[d], b[d], s);
  bf[q * CC + c] = s;
}

// ---------------------------------------------------------------------------
// Encoder split-f16 3-term MFMA NT GEMM, XCD-swizzled.
// NEW this round: counted-vmcnt 2-phase double-buffer (T3/T4). Loads for the
// next K-chunk stay in flight across the barrier (vmcnt(8) waits only the
// previous chunk's 8). LDS 64 KB/block -> still 2 blocks/CU.
// ---------------------------------------------------------------------------
__global__ __launch_bounds__(256, 2) void hgemm3s_nt(
    const _Float16* __restrict__ Ahi, const _Float16* __restrict__ Alo,
    const _Float16* __restrict__ Whi, const _Float16* __restrict__ Wlo,
    const float* __restrict__ bias, float invsc, _Float16* __restrict__ Chi,
    _Float16* __restrict__ Clo, int ldc, int K, float* __restrict__ stats,
    int N) {
  __shared__ _Float16 Ah[2][4 * 128 * 8];
  __shared__ _Float16 Al[2][4 * 128 * 8];
  __shared__ _Float16 Bh[2][4 * 128 * 8];
  __shared__ _Float16 Bl[2][4 * 128 * 8];
  int BX, BY;
  xcd_swizzle(BX, BY);
  const int tid = threadIdx.x;
  const int l = tid & 63;
  const int w = tid >> 6;
  const int m0 = BY * 128, n0 = BX * 128;
  const int wrow = (w >> 1) * 64, wcol = (w & 1) * 64;

  const int s0 = tid, s1 = tid + 256;
  const int r0 = s0 & 127, kp0 = s0 >> 7;
  const int r1 = s1 & 127, kp1 = s1 >> 7;
  const size_t a0o = (size_t)(m0 + r0) * K + kp0 * 8;
  const size_t a1o = (size_t)(m0 + r1) * K + kp1 * 8;
  const size_t w0o = (size_t)(n0 + r0) * K + kp0 * 8;
  const size_t w1o = (size_t)(n0 + r1) * K + kp1 * 8;

  f32x4 acc[4][4] = {};

  auto stage = [&](int buf, int kb) {
    GLOAD_LDS16(Ahi + a0o + kb, &Ah[buf][s0 * 8]);
    GLOAD_LDS16(Ahi + a1o + kb, &Ah[buf][s1 * 8]);
    GLOAD_LDS16(Alo + a0o + kb, &Al[buf][s0 * 8]);
    GLOAD_LDS16(Alo + a1o + kb, &Al[buf][s1 * 8]);
    GLOAD_LDS16(Whi + w0o + kb, &Bh[buf][s0 * 8]);
    GLOAD_LDS16(Whi + w1o + kb, &Bh[buf][s1 * 8]);
    GLOAD_LDS16(Wlo + w0o + kb, &Bl[buf][s0 * 8]);
    GLOAD_LDS16(Wlo + w1o + kb, &Bl[buf][s1 * 8]);
  };
  auto compute = [&](int buf) {
    half8 ah[4], al[4], bh[4], bl[4];
#pragma unroll
    for (int i = 0; i < 4; i++) {
      const int idx = (((l >> 4) << 7) + wrow + i * 16 + (l & 15)) * 8;
      ah[i] = *(const half8*)&Ah[buf][idx];
      al[i] = *(const half8*)&Al[buf][idx];
    }
#pragma unroll
    for (int j = 0; j < 4; j++) {
      const int idx = (((l >> 4) << 7) + wcol + j * 16 + (l & 15)) * 8;
      bh[j] = *(const half8*)&Bh[buf][idx];
      bl[j] = *(const half8*)&Bl[buf][idx];
    }
#pragma unroll
    for (int i = 0; i < 4; i++)
#pragma unroll
      for (int j = 0; j < 4; j++) {
        acc[i][j] = __builtin_amdgcn_mfma_f32_16x16x32_f16(ah[i], bh[j],
                                                           acc[i][j], 0, 0, 0);
        acc[i][j] = __builtin_amdgcn_mfma_f32_16x16x32_f16(al[i], bh[j],
                                                           acc[i][j], 0, 0, 0);
        acc[i][j] = __builtin_amdgcn_mfma_f32_16x16x32_f16(ah[i], bl[j],
                                                           acc[i][j], 0, 0, 0);
      }
  };

  stage(0, 0);
  int cur = 0;
  for (int kb = 32; kb < K; kb += 32) {
    stage(cur ^ 1, kb);     // 8 more loads in flight during compute
    S_VMCNT8();             // wait only the previous chunk's 8
    S_BARRIER();            // all waves' chunk-cur loads landed
    compute(cur);
    S_BARRIER();            // all waves done reading chunk-cur (WAR guard)
    cur ^= 1;
  }
  S_VMCNT0();
  S_BARRIER();
  compute(cur);

#pragma unroll
  for (int j = 0; j < 4; j++) {
    const int col = n0 + wcol + j * 16 + (l & 15);
    const float bb = bias[col];
    float s1v = 0.f, s2v = 0.f;
#pragma unroll
    for (int i = 0; i < 4; i++) {
#pragma unroll
      for (int r = 0; r < 4; r++) {
        float v = fmaf(acc[i][j][r], invsc, bb);
        const int row = m0 + wrow + i * 16 + ((l >> 4) << 2) + r;
        _Float16 hv = (_Float16)v;
        Chi[(size_t)row * ldc + col] = hv;
        Clo[(size_t)row * ldc + col] = (_Float16)(v - (float)hv);
        s1v += v;
        s2v = fmaf(v, v, s2v);
      }
    }
    s1v += __shfl_xor(s1v, 16); s1v += __shfl_xor(s1v, 32);
    s2v += __shfl_xor(s2v, 16); s2v += __shfl_xor(s2v, 32);
    if (l < 16) {
      atomicAdd(&stats[col], s1v);
      atomicAdd(&stats[N + col], s2v);
    }
  }
}

// ---------------------------------------------------------------------------
// split-f16 3-term MFMA GEMM + dual argmax, XCD-swizzled — UNCHANGED from the
// proven round-4 baseline (dbuf here would cost the 2nd block/CU; gated on
// this round's encoder-GEMM outcome).
// ---------------------------------------------------------------------------
__global__ __launch_bounds__(512, 4) void hgemm3_wo_argmax(
    const _Float16* __restrict__ Ahi, const _Float16* __restrict__ Alo,
    const _Float16* __restrict__ Whi, const _Float16* __restrict__ Wlo,
    const float* __restrict__ bf, const float* __restrict__ u,
    const float* __restrict__ log_temps, float* __restrict__ out_idx,
    int* __restrict__ idx2) {
  __shared__ _Float16 Ahs[4 * 128 * 8];
  __shared__ _Float16 Als[4 * 128 * 8];
  __shared__ _Float16 Bhs[4 * 256 * 8];
  __shared__ _Float16 Bls[4 * 256 * 8];
  __shared__ float redv[2][128][4];
  __shared__ int   redi[2][128][4];
  int BX, BY;
  xcd_swizzle(BX, BY);
  const int tid = threadIdx.x;
  const int l = tid & 63;
  const int w = tid >> 6;
  const int q = BX;
  const int m0 = BY * 128;
  const int n0 = q * CC;
  const int wrow = (w >> 2) * 64, wcol = (w & 3) * 64;

  const int ar = tid & 127, akp = tid >> 7;
  const _Float16* Agh = Ahi + (size_t)(m0 + ar) * HID + akp * 8;
  const _Float16* Agl = Alo + (size_t)(m0 + ar) * HID + akp * 8;
  _Float16* Ahd = &Ahs[tid * 8];
  _Float16* Ald = &Als[tid * 8];
  const int s0 = tid, s1 = tid + 512;
  const int br0 = s0 & 255, bkp0 = s0 >> 8;
  const int br1 = s1 & 255, bkp1 = s1 >> 8;
  const _Float16* Bgh0 = Whi + (size_t)(n0 + br0) * HID + bkp0 * 8;
  const _Float16* Bgh1 = Whi + (size_t)(n0 + br1) * HID + bkp1 * 8;
  const _Float16* Bgl0 = Wlo + (size_t)(n0 + br0) * HID + bkp0 * 8;
  const _Float16* Bgl1 = Wlo + (size_t)(n0 + br1) * HID + bkp1 * 8;
  _Float16* Bhd0 = &Bhs[s0 * 8]; _Float16* Bhd1 = &Bhs[s1 * 8];
  _Float16* Bld0 = &Bls[s0 * 8]; _Float16* Bld1 = &Bls[s1 * 8];

  f32x4 acc[4][4] = {};

  for (int kb = 0; kb < HID; kb += 32) {
    __syncthreads();
    GLOAD_LDS16(Agh + kb, Ahd);
    GLOAD_LDS16(Agl + kb, Ald);
    GLOAD_LDS16(Bgh0 + kb, Bhd0);
    GLOAD_LDS16(Bgh1 + kb, Bhd1);
    GLOAD_LDS16(Bgl0 + kb, Bld0);
    GLOAD_LDS16(Bgl1 + kb, Bld1);
    __syncthreads();
    half8 ah[4], al[4], bh[4], bl[4];
#pragma unroll
    for (int i = 0; i < 4; i++) {
      const int idx = ((l >> 4) * 128 + wrow + i * 16 + (l & 15)) * 8;
      ah[i] = *(const half8*)&Ahs[idx];
      al[i] = *(const half8*)&Als[idx];
    }
#pragma unroll
    for (int j = 0; j < 4; j++) {
      const int idx = ((l >> 4) * 256 + wcol + j * 16 + (l & 15)) * 8;
      bh[j] = *(const half8*)&Bhs[idx];
      bl[j] = *(const half8*)&Bls[idx];
    }
#pragma unroll
    for (int i = 0; i < 4; i++)
#pragma unroll
      for (int j = 0; j < 4; j++) {
        acc[i][j] = __builtin_amdgcn_mfma_f32_16x16x32_f16(ah[i], bh[j],
                                                           acc[i][j], 0, 0, 0);
        acc[i][j] = __builtin_amdgcn_mfma_f32_16x16x32_f16(al[i], bh[j],
                                                           acc[i][j], 0, 0, 0);
        acc[i][j] = __builtin_amdgcn_mfma_f32_16x16x32_f16(ah[i], bl[j],
                                                           acc[i][j], 0, 0, 0);
      }
  }

  const float scale = expf(-log_temps[q]);
  float bcol[4];
#pragma unroll
  for (int j = 0; j < 4; j++) bcol[j] = bf[n0 + wcol + j * 16 + (l & 15)];

#pragma unroll
  for (int i = 0; i < 4; i++) {
#pragma unroll
    for (int r = 0; r < 4; r++) {
      const int rloc = wrow + i * 16 + ((l >> 4) << 2) + r;
      const int row = m0 + rloc;
      float bvv = -INFINITY; int bi = 0;
      float gv = -INFINITY; int gi = 0;
#pragma unroll
      for (int j = 0; j < 4; j++) {
        const int c = wcol + j * 16 + (l & 15);
        float v = acc[i][j][r] + bcol[j];
        if (v > bvv) { bvv = v; bi = c; }
        float uu = u[(size_t)row * (QQ * CC) + n0 + c];
        float uc = fminf(fmaxf(uu, 1e-9f), 1.0f);
        float g = -logf(-logf(uc) + 1e-20f);
        float y = fmaf(v, scale, g);
        if (y > gv) { gv = y; gi = c; }
      }
#pragma unroll
      for (int off = 1; off < 16; off <<= 1) {
        float b2 = __shfl_xor(bvv, off); int bi2 = __shfl_xor(bi, off);
        if (b2 > bvv || (b2 == bvv && bi2 < bi)) { bvv = b2; bi = bi2; }
        float g2 = __shfl_xor(gv, off); int gi2 = __shfl_xor(gi, off);
        if (g2 > gv || (g2 == gv && gi2 < gi)) { gv = g2; gi = gi2; }
      }
      if ((l & 15) == 0) {
        redv[0][rloc][w & 3] = bvv; redi[0][rloc][w & 3] = bi;
        redv[1][rloc][w & 3] = gv;  redi[1][rloc][w & 3] = gi;
      }
    }
  }
  __syncthreads();
  if (tid < 128) {
    float bv = redv[0][tid][0]; int bi = redi[0][tid][0];
    float gv = redv[1][tid][0]; int gi = redi[1][tid][0];
#pragma unroll
    for (int c = 1; c < 4; c++) {
      float v = redv[0][tid][c];
      if (v > bv) { bv = v; bi = redi[0][tid][c]; }
      float v2 = redv[1][tid][c];
      if (v2 > gv) { gv = v2; gi = redi[1][tid][c]; }
    }
    const int row = m0 + tid;
    out_idx[(size_t)row * QQ + q] = (float)bi;
    idx2[(size_t)row * QQ + q] = gi;
  }
}

// ---------------------------------------------------------------------------
// FP16 MFMA NT GEMM, f16 output + fused col stats (decoder layers).
// NEW: counted-vmcnt 2-phase dbuf (vmcnt(4)); LDS 32 KB -> 2+ blocks/CU.
// ---------------------------------------------------------------------------
__global__ __launch_bounds__(256, 2) void hgemm_ntf16(
    const _Float16* __restrict__ A, const _Float16* __restrict__ W,
    const float* __restrict__ bias, _Float16* __restrict__ C, int ldc, int K,
    float* __restrict__ stats, int N) {
  __shared__ _Float16 Al[2][4 * 128 * 8];
  __shared__ _Float16 Bl[2][4 * 128 * 8];
  int BX, BY;
  xcd_swizzle(BX, BY);
  const int tid = threadIdx.x;
  const int l = tid & 63;
  const int w = tid >> 6;
  const int m0 = BY * 128, n0 = BX * 128;
  const int wrow = (w >> 1) * 64, wcol = (w & 1) * 64;

  const int s0 = tid, s1 = tid + 256;
  const int r0 = s0 & 127, kp0 = s0 >> 7;
  const int r1 = s1 & 127, kp1 = s1 >> 7;
  const size_t a0o = (size_t)(m0 + r0) * K + kp0 * 8;
  const size_t a1o = (size_t)(m0 + r1) * K + kp1 * 8;
  const size_t w0o = (size_t)(n0 + r0) * K + kp0 * 8;
  const size_t w1o = (size_t)(n0 + r1) * K + kp1 * 8;

  f32x4 acc[4][4] = {};

  auto stage = [&](int buf, int kb) {
    GLOAD_LDS16(A + a0o + kb, &Al[buf][s0 * 8]);
    GLOAD_LDS16(A + a1o + kb, &Al[buf][s1 * 8]);
    GLOAD_LDS16(W + w0o + kb, &Bl[buf][s0 * 8]);
    GLOAD_LDS16(W + w1o + kb, &Bl[buf][s1 * 8]);
  };
  auto compute = [&](int buf) {
    half8 af[4], bfr[4];
#pragma unroll
    for (int i = 0; i < 4; i++)
      af[i] = *(const half8*)
          &Al[buf][(((l >> 4) << 7) + wrow + i * 16 + (l & 15)) * 8];
#pragma unroll
    for (int j = 0; j < 4; j++)
      bfr[j] = *(const half8*)
          &Bl[buf][(((l >> 4) << 7) + wcol + j * 16 + (l & 15)) * 8];
#pragma unroll
    for (int i = 0; i < 4; i++)
#pragma unroll
      for (int j = 0; j < 4; j++)
        acc[i][j] = __builtin_amdgcn_mfma_f32_16x16x32_f16(af[i], bfr[j],
                                                           acc[i][j], 0, 0, 0);
  };

  stage(0, 0);
  int cur = 0;
  for (int kb = 32; kb < K; kb += 32) {
    stage(cur ^ 1, kb);
    S_VMCNT4();
    S_BARRIER();
    compute(cur);
    S_BARRIER();
    cur ^= 1;
  }
  S_VMCNT0();
  S_BARRIER();
  compute(cur);

#pragma unroll
  for (int j = 0; j < 4; j++) {
    const int col = n0 + wcol + j * 16 + (l & 15);
    const float bb = bias[col];
    float s1v = 0.f, s2v = 0.f;
#pragma unroll
    for (int i = 0; i < 4; i++) {
#pragma unroll
      for (int r = 0; r < 4; r++) {
        float v = acc[i][j][r] + bb;
        const int row = m0 + wrow + i * 16 + ((l >> 4) << 2) + r;
        C[(size_t)row * ldc + col] = (_Float16)v;
        s1v += v;
        s2v = fmaf(v, v, s2v);
      }
    }
    s1v += __shfl_xor(s1v, 16); s1v += __shfl_xor(s1v, 32);
    s2v += __shfl_xor(s2v, 16); s2v += __shfl_xor(s2v, 32);
    if (l < 16) {
      atomicAdd(&stats[col], s1v);
      atomicAdd(&stats[N + col], s2v);
    }
  }
}

// ---------------------------------------------------------------------------
// Final FP16 MFMA NT GEMM: fp32 output + fused commit loss vs xt.
// NEW: counted-vmcnt 2-phase dbuf (vmcnt(4)).
// ---------------------------------------------------------------------------
__global__ __launch_bounds__(256, 2) void hgemm_nt_loss(
    const _Float16* __restrict__ A, const _Float16* __restrict__ W,
    const float* __restrict__ bias, float* __restrict__ C, int ldc, int K,
    const float* __restrict__ xt, float* __restrict__ out_loss) {
  __shared__ _Float16 Al[2][4 * 128 * 8];
  __shared__ _Float16 Bl[2][4 * 128 * 8];
  int BX, BY;
  xcd_swizzle(BX, BY);
  const int tid = threadIdx.x;
  const int l = tid & 63;
  const int w = tid >> 6;
  const int m0 = BY * 128, n0 = BX * 128;
  const int wrow = (w >> 1) * 64, wcol = (w & 1) * 64;

  const int s0 = tid, s1 = tid + 256;
  const int r0 = s0 & 127, kp0 = s0 >> 7;
  const int r1 = s1 & 127, kp1 = s1 >> 7;
  const size_t a0o = (size_t)(m0 + r0) * K + kp0 * 8;
  const size_t a1o = (size_t)(m0 + r1) * K + kp1 * 8;
  const size_t w0o = (size_t)(n0 + r0) * K + kp0 * 8;
  const size_t w1o = (size_t)(n0 + r1) * K + kp1 * 8;

  f32x4 acc[4][4] = {};

  auto stage = [&](int buf, int kb) {
    GLOAD_LDS16(A + a0o + kb, &Al[buf][s0 * 8]);
    GLOAD_LDS16(A + a1o + kb, &Al[buf][s1 * 8]);
    GLOAD_LDS16(W + w0o + kb, &Bl[buf][s0 * 8]);
    GLOAD_LDS16(W + w1o + kb, &Bl[buf][s1 * 8]);
  };
  auto compute = [&](int buf) {
    half8 af[4], bfr[4];
#pragma unroll
    for (int i = 0; i < 4; i++)
      af[i] = *(const half8*)
          &Al[buf][(((l >> 4) << 7) + wrow + i * 16 + (l & 15)) * 8];
#pragma unroll
    for (int j = 0; j < 4; j++)
      bfr[j] = *(const half8*)
          &Bl[buf][(((l >> 4) << 7) + wcol + j * 16 + (l & 15)) * 8];
#pragma unroll
    for (int i = 0; i < 4; i++)
#pragma unroll
      for (int j = 0; j < 4; j++)
        acc[i][j] = __builtin_amdgcn_mfma_f32_16x16x32_f16(af[i], bfr[j],
                                                           acc[i][j], 0, 0, 0);
  };

  stage(0, 0);
  int cur = 0;
  for (int kb = 32; kb < K; kb += 32) {
    stage(cur ^ 1, kb);
    S_VMCNT4();
    S_BARRIER();
    compute(cur);
    S_BARRIER();
    cur ^= 1;
  }
  S_VMCNT0();
  S_BARRIER();
  compute(cur);

  float ls = 0.f;
#pragma unroll
  for (int j = 0; j < 4; j++) {
    const int col = n0 + wcol + j * 16 + (l & 15);
    const float bb = bias[col];
#pragma unroll
    for (int i = 0; i < 4; i++) {
#pragma unroll
      for (int r = 0; r < 4; r++) {
        float v = acc[i][j][r] + bb;
        const int row = m0 + wrow + i * 16 + ((l >> 4) << 2) + r;
        C[(size_t)row * ldc + col] = v;
        float d = v - xt[(size_t)row * ldc + col];
        ls = fmaf(d, d, ls);
      }
    }
  }
#pragma unroll
  for (int off = 32; off > 0; off >>= 1) ls += __shfl_xor(ls, off);
  if (l == 0)
    atomicAdd(out_loss, ls * (1.0f / ((float)BT * (float)DIM)));
}

// ---------------------------------------------------------------------------
// BatchNorm helpers
// ---------------------------------------------------------------------------
__global__ __launch_bounds__(256) void bn_finalize(const float* __restrict__ sums,
                                                   const float* __restrict__ gamma,
                                                   const float* __restrict__ beta,
                                                   float* __restrict__ ss, int N) {
  int n = blockIdx.x * 256 + threadIdx.x;
  if (n >= N) return;
  const float invM = 1.0f / (float)BT;
  float mean = sums[n] * invM;
  float var = sums[N + n] * invM - mean * mean;
  float sc = gamma[n] / sqrtf(var + EPSB);
  ss[n] = sc;
  ss[N + n] = beta[n] - mean * sc;
}

// in-place BN (+relu) on a split (hi, lo) f16 pair
__global__ __launch_bounds__(256) void bn_resplit(_Float16* __restrict__ hi,
                                                  _Float16* __restrict__ lo,
                                                  const float* __restrict__ ss,
                                                  int nmask, int N, long n4,
                                                  int relu) {
  long stride = (long)gridDim.x * 256;
  for (long i = (long)blockIdx.x * 256 + threadIdx.x; i < n4; i += stride) {
    int col = (int)((i << 2) & nmask);
    half4 h = ((half4*)hi)[i];
    half4 L = ((half4*)lo)[i];
    float4 sc = *(const float4*)(ss + col);
    float4 sh = *(const float4*)(ss + N + col);
    float vx = fmaf((float)h.x + (float)L.x, sc.x, sh.x);
    float vy = fmaf((float)h.y + (float)L.y, sc.y, sh.y);
    float vz = fmaf((float)h.z + (float)L.z, sc.z, sh.z);
    float vw = fmaf((float)h.w + (float)L.w, sc.w, sh.w);
    if (relu) {
      vx = fmaxf(vx, 0.f); vy = fmaxf(vy, 0.f);
      vz = fmaxf(vz, 0.f); vw = fmaxf(vw, 0.f);
    }
    half4 hv, lv;
    hv.x = (_Float16)vx; lv.x = (_Float16)(vx - (float)hv.x);
    hv.y = (_Float16)vy; lv.y = (_Float16)(vy - (float)hv.y);
    hv.z = (_Float16)vz; lv.z = (_Float16)(vz - (float)hv.z);
    hv.w = (_Float16)vw; lv.w = (_Float16)(vw - (float)hv.w);
    ((half4*)hi)[i] = hv;
    ((half4*)lo)[i] = lv;
  }
}

// in-place BN (+relu) on an f16 buffer
__global__ __launch_bounds__(256) void bnf16_inplace(_Float16* __restrict__ h,
                                                     const float* __restrict__ ss,
                                                     int nmask, int N, long n4,
                                                     int relu) {
  long stride = (long)gridDim.x * 256;
  for (long i = (long)blockIdx.x * 256 + threadIdx.x; i < n4; i += stride) {
    int col = (int)((i << 2) & nmask);
    half4 v = ((half4*)h)[i];
    float4 sc = *(const float4*)(ss + col);
    float4 sh = *(const float4*)(ss + N + col);
    float vx = fmaf((float)v.x, sc.x, sh.x);
    float vy = fmaf((float)v.y, sc.y, sh.y);
    float vz = fmaf((float)v.z, sc.z, sh.z);
    float vw = fmaf((float)v.w, sc.w, sh.w);
    if (relu) {
      vx = fmaxf(vx, 0.f); vy = fmaxf(vy, 0.f);
      vz = fmaxf(vz, 0.f); vw = fmaxf(vw, 0.f);
    }
    half4 o;
    o.x = (_Float16)vx; o.y = (_Float16)vy;
    o.z = (_Float16)vz; o.w = (_Float16)vw;
    ((half4*)h)[i] = o;
  }
}

// fp32 h -> f16 out with BN scale/shift (+optional relu)
__global__ __launch_bounds__(256) void bn_apply_f16(const float* __restrict__ h,
                                                    const float* __restrict__ ss,
                                                    int nmask, int N, long n4,
                                                    int relu,
                                                    _Float16* __restrict__ o) {
  long stride = (long)gridDim.x * 256;
  for (long i = (long)blockIdx.x * 256 + threadIdx.x; i < n4; i += stride) {
    int col = (int)((i << 2) & nmask);
    float4 v = ((const float4*)h)[i];
    float4 sc = *(const float4*)(ss + col);
    float4 sh = *(const float4*)(ss + N + col);
    v.x = fmaf(v.x, sc.x, sh.x); v.y = fmaf(v.y, sc.y, sh.y);
    v.z = fmaf(v.z, sc.z, sh.z); v.w = fmaf(v.w, sc.w, sh.w);
    if (relu) {
      v.x = fmaxf(v.x, 0.f); v.y = fmaxf(v.y, 0.f);
      v.z = fmaxf(v.z, 0.f); v.w = fmaxf(v.w, 0.f);
    }
    half4 hv;
    hv.x = (_Float16)v.x; hv.y = (_Float16)v.y;
    hv.z = (_Float16)v.z; hv.w = (_Float16)v.w;
    ((half4*)o)[i] = hv;
  }
}

// fp32 -> split (hi, lo) f16 with optional pre-scale (used for Wf)
__global__ __launch_bounds__(256) void conv_split_s(const float* __restrict__ in,
                                                    _Float16* __restrict__ hi,
                                                    _Float16* __restrict__ lo,
                                                    int n4, float scale) {
  int i = blockIdx.x * 256 + threadIdx.x;
  if (i >= n4) return;
  split4(in, hi, lo, i, scale);
}

// ---------------------------------------------------------------------------
// emb[bt, d] = sum_q codebook[q, idx2[bt,q], d]  + fused column stats.
// ---------------------------------------------------------------------------
__global__ __launch_bounds__(256) void emb_gather_stats(
    const float* __restrict__ cb, const int* __restrict__ idx2,
    float* __restrict__ emb, float* __restrict__ sums) {
  __shared__ int k[64][8];
  const int r0 = blockIdx.x * 64;
  const int tid = threadIdx.x;
  for (int t = tid; t < 64 * QQ; t += 256)
    k[t >> 3][t & 7] = idx2[(size_t)(r0 + (t >> 3)) * QQ + (t & 7)];
  __syncthreads();
  const int d = tid;
  float s1 = 0.f, s2 = 0.f;
  for (int rr = 0; rr < 64; rr++) {
    float s = 0.f;
#pragma unroll
    for (int q = 0; q < QQ; q++)
      s += cb[((size_t)(q * CC + k[rr][q])) * DD + d];
    emb[(size_t)(r0 + rr) * DD + d] = s;
    s1 += s;
    s2 = fmaf(s, s, s2);
  }
  atomicAdd(&sums[d], s1);
  atomicAdd(&sums[DD + d], s2);
}

// ---------------------------------------------------------------------------
// Workspace layout (float offsets) — unchanged.
// ---------------------------------------------------------------------------
static const size_t OF_XT = 0;
static const size_t OF_R1 = OF_XT + (size_t)BT * DIM;
static const size_t OF_R2 = OF_R1 + (size_t)BT * HID;
static const size_t OF_WF = OF_R2 + (size_t)BT * HID;
static const size_t OF_BF = OF_WF + (size_t)2048 * HID;
static const size_t OF_EMBH = OF_BF + 2048;
static const size_t OF_HB = OF_EMBH + (size_t)BT * DD / 2;
static const size_t OF_W0H = OF_HB + (size_t)BT * HID / 2;
static const size_t OF_W1H = OF_W0H + (size_t)HID * DD / 2;
static const size_t OF_WFH = OF_W1H + (size_t)HID * HID / 2;
static const size_t OF_I2 = OF_WFH + (size_t)DIM * HID / 2;
static const size_t OF_ST = OF_I2 + (size_t)BT * QQ;
static const size_t OF_SS0 = OF_ST + 4096;
static const size_t OF_SS1 = OF_SS0 + 2048;
static const size_t OF_SSD = OF_SS1 + 2048;
static const size_t OF_SD0 = OF_SSD + 1024;
static const size_t OF_SD1 = OF_SD0 + 2048;

extern "C" void kernel_launch(void* const* d_in, const int* in_sizes, int n_in,
                              void* d_out, int out_size, void* d_ws, size_t ws_size,
                              hipStream_t stream) {
  const float* x        = (const float*)d_in[0];
  const float* u        = (const float*)d_in[1];
  const float* codebook = (const float*)d_in[2];
  const float* log_temps= (const float*)d_in[3];
  const float* enc_w0   = (const float*)d_in[4];
  const float* enc_b0   = (const float*)d_in[5];
  const float* enc_g0   = (const float*)d_in[6];
  const float* enc_be0  = (const float*)d_in[7];
  const float* enc_w1   = (const float*)d_in[8];
  const float* enc_b1   = (const float*)d_in[9];
  const float* enc_g1   = (const float*)d_in[10];
  const float* enc_be1  = (const float*)d_in[11];
  const float* enc_wo   = (const float*)d_in[12];
  const float* enc_bo   = (const float*)d_in[13];
  const float* dec_g    = (const float*)d_in[14];
  const float* dec_be   = (const float*)d_in[15];
  const float* dec_w0   = (const float*)d_in[16];
  const float* dec_b0   = (const float*)d_in[17];
  const float* dec_g0   = (const float*)d_in[18];
  const float* dec_be0  = (const float*)d_in[19];
  const float* dec_w1   = (const float*)d_in[20];
  const float* dec_b1   = (const float*)d_in[21];
  const float* dec_g1   = (const float*)d_in[22];
  const float* dec_be1  = (const float*)d_in[23];
  const float* fin_w    = (const float*)d_in[24];
  const float* fin_b    = (const float*)d_in[25];

  float* ws = (float*)d_ws;
  float* xt = ws + OF_XT;
  float* R1 = ws + OF_R1;
  float* Wf = ws + OF_WF;
  float* bfold = ws + OF_BF;
  _Float16* embh = (_Float16*)(ws + OF_EMBH);
  _Float16* w0h = (_Float16*)(ws + OF_W0H);
  _Float16* w1h = (_Float16*)(ws + OF_W1H);
  _Float16* wfh = (_Float16*)(ws + OF_WFH);
  int* idx2 = (int*)(ws + OF_I2);
  float* st = ws + OF_ST;
  float* ss0 = ws + OF_SS0;
  float* ss1 = ws + OF_SS1;
  float* ssd = ws + OF_SSD;
  float* sd0 = ws + OF_SD0;
  float* sd1 = ws + OF_SD1;

  // aliased split / f16 buffers (lifetimes verified rounds 2-4)
  _Float16* xthi = (_Float16*)(ws + OF_R2);
  _Float16* xtlo = (_Float16*)(ws + OF_R2 + (size_t)BT * DIM / 2);
  _Float16* w0hi = (_Float16*)(ws + OF_R2 + (size_t)BT * DIM);
  _Float16* w0lo = (_Float16*)(ws + OF_R2 + (size_t)BT * DIM + (size_t)HID * DIM / 2);
  _Float16* w1hi = (_Float16*)(ws + OF_R2 + (size_t)BT * DIM + (size_t)HID * DIM);
  _Float16* w1lo = (_Float16*)(ws + OF_R2 + (size_t)BT * DIM + (size_t)HID * DIM +
                               (size_t)HID * HID / 2);
  _Float16* r1hi = (_Float16*)(ws + OF_R1);
  _Float16* r1lo = (_Float16*)(ws + OF_R1 + (size_t)BT * HID / 2);
  _Float16* r2hi = (_Float16*)(ws + OF_HB);
  _Float16* r2lo = (_Float16*)(ws + OF_R2);
  _Float16* wfhi = (_Float16*)(ws + OF_R1);
  _Float16* wflo = (_Float16*)(ws + OF_R1 + (size_t)2048 * HID / 2);
  _Float16* h16a = (_Float16*)(ws + OF_R2);
  _Float16* h16b = (_Float16*)(ws + OF_R2 + (size_t)BT * HID / 2);

  float* out = (float*)d_out;
  float* out_idx = out + (size_t)BT * DIM;
  float* out_loss = out + (size_t)BT * DIM + (size_t)BT * QQ;

  hipMemsetAsync(out_loss, 0, sizeof(float), stream);

  // weight prep (merged) + codebook folding
  prep_weights<<<dim3(3328), 256, 0, stream>>>(
      dec_w0, dec_w1, fin_w, enc_w0, enc_w1, w0h, w1h, wfh, w0hi, w0lo, w1hi,
      w1lo);
  fold_w<<<dim3(HID / 128, 2048 / 128), 256, 0, stream>>>(codebook, enc_wo, Wf);
  fold_b<<<dim3(QQ), 256, 0, stream>>>(codebook, enc_bo, bfold);

  // 1. transpose (+ split f16 copies of xt)
  transpose_xt<<<dim3(TT / 32, DIM / 32, BB), dim3(32, 8), 0, stream>>>(
      x, xt, xthi, xtlo);

  // 2. enc0: r1 = xt @ enc_w0^T + b0 (split MFMA, stats fused); BN in place
  hipMemsetAsync(st, 0, 2 * HID * sizeof(float), stream);
  hgemm3s_nt<<<dim3(HID / 128, BT / 128), 256, 0, stream>>>(
      xthi, xtlo, w0hi, w0lo, enc_b0, 1.f / 64.f, r1hi, r1lo, HID, DIM, st, HID);
  bn_finalize<<<dim3(4), 256, 0, stream>>>(st, enc_g0, enc_be0, ss0, HID);
  bn_resplit<<<dim3(2048), 256, 0, stream>>>(r1hi, r1lo, ss0, HID - 1, HID,
                                             (long)BT * HID / 4, 1);

  // 3. enc1: r2 = r1 @ enc_w1^T + b1 (split MFMA, stats fused); BN in place
  hipMemsetAsync(st, 0, 2 * HID * sizeof(float), stream);
  hgemm3s_nt<<<dim3(HID / 128, BT / 128), 256, 0, stream>>>(
      r1hi, r1lo, w1hi, w1lo, enc_b1, 1.f / 64.f, r2hi, r2lo, HID, HID, st, HID);
  conv_split_s<<<dim3(2048 * HID / 4 / 256), 256, 0, stream>>>(
      Wf, wfhi, wflo, 2048 * HID / 4, 1.f);
  bn_finalize<<<dim3(4), 256, 0, stream>>>(st, enc_g1, enc_be1, ss1, HID);
  bn_resplit<<<dim3(2048), 256, 0, stream>>>(r2hi, r2lo, ss1, HID - 1, HID,
                                             (long)BT * HID / 4, 1);

  // 4. split-f16 MFMA wo-GEMM + argmax epilogue
  hgemm3_wo_argmax<<<dim3(QQ, BT / 128), 512, 0, stream>>>(
      r2hi, r2lo, wfhi, wflo, bfold, u, log_temps, out_idx, idx2);

  // 5. emb gather (+fused col stats) + BN -> f16
  hipMemsetAsync(st, 0, 2 * DD * sizeof(float), stream);
  emb_gather_stats<<<dim3(BT / 64), 256, 0, stream>>>(codebook, idx2, R1, st);
  bn_finalize<<<dim3(1), 256, 0, stream>>>(st, dec_g, dec_be, ssd, DD);
  bn_apply_f16<<<dim3(2048), 256, 0, stream>>>(R1, ssd, DD - 1, DD,
                                               (long)BT * DD / 4, 0, embh);

  // 6. decoder FFN in f16 MFMA (f16 output + in-place BN)
  hipMemsetAsync(st, 0, 2 * HID * sizeof(float), stream);
  hgemm_ntf16<<<dim3(HID / 128, BT / 128), 256, 0, stream>>>(
      embh, w0h, dec_b0, h16a, HID, DD, st, HID);
  bn_finalize<<<dim3(4), 256, 0, stream>>>(st, dec_g0, dec_be0, sd0, HID);
  bnf16_inplace<<<dim3(2048), 256, 0, stream>>>(h16a, sd0, HID - 1, HID,
                                                (long)BT * HID / 4, 1);

  hipMemsetAsync(st, 0, 2 * HID * sizeof(float), stream);
  hgemm_ntf16<<<dim3(HID / 128, BT / 128), 256, 0, stream>>>(
      h16a, w1h, dec_b1, h16b, HID, HID, st, HID);
  bn_finalize<<<dim3(4), 256, 0, stream>>>(st, dec_g1, dec_be1, sd1, HID);
  bnf16_inplace<<<dim3(2048), 256, 0, stream>>>(h16b, sd1, HID - 1, HID,
                                                (long)BT * HID / 4, 1);

  // 7. x_reco = h @ fin_w^T + fin_b  (+fused commit loss vs xt)
  hgemm_nt_loss<<<dim3(DIM / 128, BT / 128), 256, 0, stream>>>(
      h16b, wfh, fin_b, out, DIM, HID, xt, out_loss);
}